// Round 12
// baseline (134.878 us; speedup 1.0000x reference)
//
#include <hip/hip_runtime.h>
#include <stdint.h>

#define NN   4096
#define KK   32
#define HID  128
#define BLK  256
#define NPB  2
#define GRID (NN / NPB)
#define CAP  128

typedef unsigned short bf16_t;
typedef __attribute__((ext_vector_type(8))) short bf16x8;
typedef __attribute__((ext_vector_type(4))) float f32x4;

__device__ __forceinline__ bf16_t f2bf(float f) {
    uint32_t u = __float_as_uint(f);
    u = u + 0x7fffu + ((u >> 16) & 1u);   // round-to-nearest-even
    return (bf16_t)(u >> 16);
}
__device__ __forceinline__ float siluf(float x) {
    return x / (1.0f + __expf(-x));
}

// ---- prepack: W2 fp32 -> bf16 in MFMA B-fragment order ----
__global__ __launch_bounds__(BLK) void prepack_w2(
    const float* __restrict__ W2, uint4* __restrict__ w2b)
{
    int c  = blockIdx.x * BLK + threadIdx.x;
    int f  = c >> 6, ln = c & 63;
    int NT = f >> 2, kk = f & 3;
    int row = NT*16 + (ln & 15);
    int k0  = kk*32 + (ln >> 4) * 8;
    const float* s = W2 + row * HID + k0;
    float4 lo = *(const float4*)s;
    float4 hi = *(const float4*)(s + 4);
    uint4 pk;
    pk.x = (uint32_t)f2bf(lo.x) | ((uint32_t)f2bf(lo.y) << 16);
    pk.y = (uint32_t)f2bf(lo.z) | ((uint32_t)f2bf(lo.w) << 16);
    pk.z = (uint32_t)f2bf(hi.x) | ((uint32_t)f2bf(hi.y) << 16);
    pk.w = (uint32_t)f2bf(hi.z) | ((uint32_t)f2bf(hi.w) << 16);
    w2b[c] = pk;
}

template<bool WS>
struct __align__(16) Sm {
    union __align__(16) {                 // phase-disjoint reuse
        uint32_t hist[NPB][1024];         // 8 KB: histogram of SAMPLE MINS only
        ushort h1[64 * HID];              // 16 KB: MLP A-operand, bf16, swizzled
    } u;
    uint32_t w2l[WS ? 4 : HID * 64];      // W2 LDS staging only in fallback
    unsigned long long cand[NPB][CAP];    // 2 KB
    float sedge[64];
    int recvs[NPB][KK];
    int waveTot[NPB][4];
    unsigned long long redk[4];
    int pivotB[NPB];
    int cnt[NPB];
    int chosen;
};

template<bool WS>
__global__ __launch_bounds__(BLK) void egnn_main(
    const float* __restrict__ pos, const float* __restrict__ tptr,
    const float* __restrict__ W1,  const float* __restrict__ b1,
    const float* __restrict__ g1,  const float* __restrict__ W2,
    const float* __restrict__ b2,  const float* __restrict__ g2,
    const float* __restrict__ W3,  const float* __restrict__ b3,
    const uint4* __restrict__ w2b, float* __restrict__ out)
{
    __shared__ Sm<WS> sm;
    const int tid  = threadIdx.x;
    const int lane = tid & 63;
    const int wid  = tid >> 6;
    const int bid  = blockIdx.x;
    const int i0   = NPB * bid, i1 = i0 + 1;
    const int l15  = lane & 15, lq = lane >> 4;

    const float ts  = tptr[0];
    const float b3s = b3[0];

    // closed-form RMS coefficients: sum_n (rad*a_n + c_n)^2 = rad^2*A2 + 2*rad*AC + C2
    float A2, AC, C2;
    {
        const float4 w1v = ((const float4*)W1)[lane];     // rows 2l,2l+1
        const float2 b1v = ((const float2*)b1)[lane];
        float t0 = ts * w1v.y + b1v.x;
        float t1 = ts * w1v.w + b1v.y;
        A2 = w1v.x*w1v.x + w1v.z*w1v.z;
        AC = w1v.x*t0    + w1v.z*t1;
        C2 = t0*t0       + t1*t1;
        #pragma unroll
        for (int m = 32; m >= 1; m >>= 1) {
            A2 += __shfl_xor(A2, m, 64);
            AC += __shfl_xor(AC, m, 64);
            C2 += __shfl_xor(C2, m, 64);
        }
    }

    if constexpr (!WS) {
        for (int idx = tid; idx < HID * 16; idx += BLK) {
            int row = idx >> 4, c = idx & 15;
            const float* src = W2 + row * HID + c * 8;
            float4 lo = *(const float4*)src;
            float4 hi = *(const float4*)(src + 4);
            uint4 pk;
            pk.x = (uint32_t)f2bf(lo.x) | ((uint32_t)f2bf(lo.y) << 16);
            pk.y = (uint32_t)f2bf(lo.z) | ((uint32_t)f2bf(lo.w) << 16);
            pk.z = (uint32_t)f2bf(hi.x) | ((uint32_t)f2bf(hi.y) << 16);
            pk.w = (uint32_t)f2bf(hi.z) | ((uint32_t)f2bf(hi.w) << 16);
            *((uint4*)&sm.w2l[row * 64 + 4 * (c ^ (row & 15))]) = pk;
        }
    }
    // zero sample histograms: 2048 dwords = 512 uint4, 2 per thread
    {
        uint4 z = uint4{0u, 0u, 0u, 0u};
        uint4* hz = (uint4*)sm.u.hist;
        hz[tid] = z; hz[tid + 256] = z;
    }
    if (tid == 0) { sm.cnt[0] = 0; sm.cnt[1] = 0; }
    __syncthreads();                                            // B1

    // node centers: pos[6*bid .. +5] as 3x float2
    const float2 c01 = ((const float2*)pos)[3*bid    ];
    const float2 c23 = ((const float2*)pos)[3*bid + 1];
    const float2 c45 = ((const float2*)pos)[3*bid + 2];
    const float px0 = c01.x, py0 = c01.y, pz0 = c23.x;
    const float px1 = c23.y, py1 = c45.x, pz1 = c45.y;

    // ---- distances for BOTH nodes into registers (no per-j atomics) ----
    float dreg0[4][4], dreg1[4][4];
    {
        const float4* p4 = (const float4*)pos;
        #pragma unroll
        for (int g = 0; g < 4; ++g) {
            float4 f0 = p4[768*g + 3*tid];
            float4 f1 = p4[768*g + 3*tid + 1];
            float4 f2 = p4[768*g + 3*tid + 2];
            float jx[4] = {f0.x, f0.w, f1.z, f2.y};
            float jy[4] = {f0.y, f1.x, f1.w, f2.z};
            float jz[4] = {f0.z, f1.y, f2.x, f2.w};
            #pragma unroll
            for (int c = 0; c < 4; ++c) {
                float dx0 = px0 - jx[c], dy0 = py0 - jy[c], dz0 = pz0 - jz[c];
                dreg0[g][c] = __fadd_rn(__fadd_rn(__fmul_rn(dx0,dx0), __fmul_rn(dy0,dy0)),
                                        __fmul_rn(dz0,dz0));
                float dx1 = px1 - jx[c], dy1 = py1 - jy[c], dz1 = pz1 - jz[c];
                dreg1[g][c] = __fadd_rn(__fadd_rn(__fmul_rn(dx1,dx1), __fmul_rn(dy1,dy1)),
                                        __fmul_rn(dz1,dz1));
            }
        }
    }
    // patch self BEFORE sampling (keeps the sample-min pivot bound exact)
    if (((i0 & 1023) >> 2) == tid) dreg0[i0 >> 10][i0 & 3] = __uint_as_float(0x7f800000u);
    if (((i1 & 1023) >> 2) == tid) dreg1[i1 >> 10][i1 & 3] = __uint_as_float(0x7f800000u);

    // ---- per-thread sample mins (VALU only), ONE histogram atomic per node ----
    {
        float m0 = dreg0[0][0], m1 = dreg1[0][0];
        #pragma unroll
        for (int g = 0; g < 4; ++g)
            #pragma unroll
            for (int c = 0; c < 4; ++c) {
                if (g | c) {
                    m0 = fminf(m0, dreg0[g][c]);
                    m1 = fminf(m1, dreg1[g][c]);
                }
            }
        atomicAdd((int*)&sm.u.hist[0][__float_as_uint(m0) >> 21], 1);
        atomicAdd((int*)&sm.u.hist[1][__float_as_uint(m1) >> 21], 1);
    }
    __syncthreads();                                            // B2

    // ---- pivot bucket B: first bucket where cumulative SAMPLE count >= KK ----
    // >=KK sample-mins (distinct j!) lie at or below UB(B) => v_32 <= UB(B):
    // candidate set {bucket(d)<=B} provably contains the exact top-KK.
    {
        const int b0 = tid * 4;
        uint4 qa = *(const uint4*)&sm.u.hist[0][b0];
        uint4 qb = *(const uint4*)&sm.u.hist[1][b0];
        int a0 = (int)qa.x, a1 = (int)qa.y, a2 = (int)qa.z, a3 = (int)qa.w;
        int e0 = (int)qb.x, e1 = (int)qb.y, e2 = (int)qb.z, e3 = (int)qb.w;
        int s0 = a0+a1+a2+a3, s1 = e0+e1+e2+e3;
        int in0 = s0, in1 = s1;
        #pragma unroll
        for (int off = 1; off < 64; off <<= 1) {
            int v0 = __shfl_up(in0, off, 64);
            int v1 = __shfl_up(in1, off, 64);
            if (lane >= off) { in0 += v0; in1 += v1; }
        }
        if (lane == 63) { sm.waveTot[0][wid] = in0; sm.waveTot[1][wid] = in1; }
        __syncthreads();                                        // B3
        int base0 = 0, base1 = 0;
        for (int w = 0; w < wid; ++w) { base0 += sm.waveTot[0][w]; base1 += sm.waveTot[1][w]; }
        int E0 = base0 + in0 - s0;
        if (E0 < KK && E0 + s0 >= KK) {
            int cum = E0, B = b0 + 3;
            if (cum + a0 >= KK) B = b0;
            else { cum += a0;
                if (cum + a1 >= KK) B = b0 + 1;
                else { cum += a1; if (cum + a2 >= KK) B = b0 + 2; }
            }
            sm.pivotB[0] = B;
        }
        int E1 = base1 + in1 - s1;
        if (E1 < KK && E1 + s1 >= KK) {
            int cum = E1, B = b0 + 3;
            if (cum + e0 >= KK) B = b0;
            else { cum += e0;
                if (cum + e1 >= KK) B = b0 + 1;
                else { cum += e1; if (cum + e2 >= KK) B = b0 + 2; }
            }
            sm.pivotB[1] = B;
        }
    }
    __syncthreads();                                            // B4

    // ---- compaction (both nodes) ----
    {
        const int B0 = sm.pivotB[0], B1v = sm.pivotB[1];
        #pragma unroll
        for (int g = 0; g < 4; ++g) {
            #pragma unroll
            for (int c = 0; c < 4; ++c) {
                uint32_t ub0 = __float_as_uint(dreg0[g][c]);   // self=inf -> bucket>B
                if ((int)(ub0 >> 21) <= B0) {
                    int slot = atomicAdd(&sm.cnt[0], 1);
                    if (slot < CAP)
                        sm.cand[0][slot] = (((unsigned long long)ub0) << 12)
                                         | (unsigned)(1024*g + 4*tid + c);
                }
                uint32_t ub1 = __float_as_uint(dreg1[g][c]);
                if ((int)(ub1 >> 21) <= B1v) {
                    int slot = atomicAdd(&sm.cnt[1], 1);
                    if (slot < CAP)
                        sm.cand[1][slot] = (((unsigned long long)ub1) << 12)
                                         | (unsigned)(1024*g + 4*tid + c);
                }
            }
        }
    }
    __syncthreads();                                            // B5

    const int c0 = sm.cnt[0], c1v = sm.cnt[1];
    if (c0 <= CAP && c1v <= CAP) {
        // threads 0..127 rank node0 cands; 128..255 rank node1
        int nn = tid >> 7, tt = tid & 127;
        int cN = nn ? c1v : c0;
        if (tt < cN) {
            unsigned long long km = sm.cand[nn][tt];
            int rank = 0;
            for (int q = 0; q < cN; ++q)
                rank += (sm.cand[nn][q] < km) ? 1 : 0;
            if (rank < KK) sm.recvs[nn][rank] = (int)(km & 0xFFFull);
        }
    } else {
        // cold fallback (overflow): exact 32-pass argmin, node 0 then node 1
        for (int it = 0; it < KK; ++it) {
            unsigned long long best = ~0ull;
            #pragma unroll
            for (int g = 0; g < 4; ++g)
                #pragma unroll
                for (int c = 0; c < 4; ++c) {
                    unsigned long long key =
                        (((unsigned long long)__float_as_uint(dreg0[g][c])) << 12)
                        | (unsigned)(1024*g + 4*tid + c);
                    best = best < key ? best : key;
                }
            #pragma unroll
            for (int m = 32; m >= 1; m >>= 1) {
                unsigned long long o = __shfl_xor(best, m, 64);
                best = best < o ? best : o;
            }
            if (lane == 0) sm.redk[wid] = best;
            __syncthreads();
            if (tid == 0) {
                unsigned long long b01 = sm.redk[0] < sm.redk[1] ? sm.redk[0] : sm.redk[1];
                unsigned long long b23 = sm.redk[2] < sm.redk[3] ? sm.redk[2] : sm.redk[3];
                unsigned long long b   = b01 < b23 ? b01 : b23;
                int j = (int)(b & 0xfffull);
                sm.recvs[0][it] = j; sm.chosen = j;
            }
            __syncthreads();
            int j = sm.chosen;
            if (((j & 1023) >> 2) == tid) dreg0[j >> 10][j & 3] = __uint_as_float(0x7f800000u);
        }
        for (int it = 0; it < KK; ++it) {
            unsigned long long best = ~0ull;
            #pragma unroll
            for (int g = 0; g < 4; ++g)
                #pragma unroll
                for (int c = 0; c < 4; ++c) {
                    unsigned long long key =
                        (((unsigned long long)__float_as_uint(dreg1[g][c])) << 12)
                        | (unsigned)(1024*g + 4*tid + c);
                    best = best < key ? best : key;
                }
            #pragma unroll
            for (int m = 32; m >= 1; m >>= 1) {
                unsigned long long o = __shfl_xor(best, m, 64);
                best = best < o ? best : o;
            }
            if (lane == 0) sm.redk[wid] = best;
            __syncthreads();
            if (tid == 0) {
                unsigned long long b01 = sm.redk[0] < sm.redk[1] ? sm.redk[0] : sm.redk[1];
                unsigned long long b23 = sm.redk[2] < sm.redk[3] ? sm.redk[2] : sm.redk[3];
                unsigned long long b   = b01 < b23 ? b01 : b23;
                int j = (int)(b & 0xfffull);
                sm.recvs[1][it] = j; sm.chosen = j;
            }
            __syncthreads();
            int j = sm.chosen;
            if (((j & 1023) >> 2) == tid) dreg1[j >> 10][j & 3] = __uint_as_float(0x7f800000u);
        }
    }
    __syncthreads();                                            // B6

    // ---- layer 1 fused with edge gather; writes wave-local h1 rows as b128 ----
    {
        const int ch = lane >> 2, epr = lane & 3;
        float4 wA = ((const float4*)W1)[ch*4    ];
        float4 wB = ((const float4*)W1)[ch*4 + 1];
        float4 wC = ((const float4*)W1)[ch*4 + 2];
        float4 wD = ((const float4*)W1)[ch*4 + 3];
        float4 bA = ((const float4*)b1)[ch*2], bB = ((const float4*)b1)[ch*2 + 1];
        float4 gA = ((const float4*)g1)[ch*2], gB = ((const float4*)g1)[ch*2 + 1];
        float av[8] = {wA.x, wA.z, wB.x, wB.z, wC.x, wC.z, wD.x, wD.z};
        float cv[8] = {ts*wA.y + bA.x, ts*wA.w + bA.y, ts*wB.y + bA.z, ts*wB.w + bA.w,
                       ts*wC.y + bB.x, ts*wC.w + bB.y, ts*wD.y + bB.z, ts*wD.w + bB.w};
        float gv[8] = {gA.x, gA.y, gA.z, gA.w, gB.x, gB.y, gB.z, gB.w};

        const int nodeW = wid >> 1;
        const float pxw = nodeW ? px1 : px0;
        const float pyw = nodeW ? py1 : py0;
        const float pzw = nodeW ? pz1 : pz0;
        uint4* h1q = (uint4*)sm.u.h1;
        #pragma unroll
        for (int g = 0; g < 4; ++g) {
            int E = 16*wid + 4*g + epr;
            int r = sm.recvs[nodeW][E & 31];
            float dx = pxw - pos[3*r];
            float dy = pyw - pos[3*r+1];
            float dz = pzw - pos[3*r+2];
            float rad = __fadd_rn(__fadd_rn(__fmul_rn(dx,dx), __fmul_rn(dy,dy)),
                                  __fmul_rn(dz,dz));
            float sqv = rad*rad*A2 + 2.0f*rad*AC + C2;
            float rn  = rsqrtf(sqv * (1.0f/HID) + 1e-5f);
            uint32_t pk[4];
            #pragma unroll
            for (int p = 0; p < 4; ++p) {
                float va = siluf((rad*av[2*p]   + cv[2*p])   * rn * gv[2*p]);
                float vb = siluf((rad*av[2*p+1] + cv[2*p+1]) * rn * gv[2*p+1]);
                pk[p] = (__float_as_uint(va) >> 16) | (__float_as_uint(vb) & 0xffff0000u);
            }
            h1q[E*16 + (ch ^ (E & 15))] = uint4{pk[0], pk[1], pk[2], pk[3]};
        }
    }
    // no barrier: h1 rows [16w,16w+16) are written and read only by wave w

    // ---- layer 2 via MFMA: wave w = m-tile w (16 edges), ALL 8 n-tiles ----
    f32x4 acc[8];
    #pragma unroll
    for (int nt = 0; nt < 8; ++nt) acc[nt] = f32x4{0.f, 0.f, 0.f, 0.f};
    {
        const bf16x8* h1v = (const bf16x8*)sm.u.h1;   // [64][16 chunks]
        const int m = 16*wid + l15;
        if constexpr (WS) {
            const bf16x8* bv = (const bf16x8*)w2b;
            #pragma unroll
            for (int kk = 0; kk < 4; ++kk) {
                bf16x8 af = h1v[m*16 + ((kk*4 + lq) ^ l15)];
                #pragma unroll
                for (int nt = 0; nt < 8; ++nt)
                    acc[nt] = __builtin_amdgcn_mfma_f32_16x16x32_bf16(
                                  af, bv[(nt*4 + kk)*64 + lane], acc[nt], 0, 0, 0);
            }
        } else {
            const bf16x8* w2v = (const bf16x8*)sm.w2l;    // [128][16 chunks]
            #pragma unroll
            for (int kk = 0; kk < 4; ++kk) {
                const int q = (kk*4 + lq) ^ l15;
                bf16x8 af = h1v[m*16 + q];
                #pragma unroll
                for (int nt = 0; nt < 8; ++nt)
                    acc[nt] = __builtin_amdgcn_mfma_f32_16x16x32_bf16(
                                  af, w2v[(nt*16 + l15)*16 + q], acc[nt], 0, 0, 0);
            }
        }
    }

    // ---- epilogue (fully wave-local): n = nt*16 + l15 ----
    float g2v[8], w3v[8], b2v[8];
    #pragma unroll
    for (int nt = 0; nt < 8; ++nt) {
        int n = nt*16 + l15;
        g2v[nt] = g2[n]; w3v[nt] = W3[n]; b2v[nt] = b2[n];
    }
    float ss[4];
    #pragma unroll
    for (int r = 0; r < 4; ++r) {
        float t = 0.f;
        #pragma unroll
        for (int nt = 0; nt < 8; ++nt) {
            float zz = acc[nt][r] + b2v[nt];
            acc[nt][r] = zz;
            t += zz*zz;
        }
        ss[r] = t;
    }
    #pragma unroll
    for (int m = 8; m >= 1; m >>= 1) {
        #pragma unroll
        for (int r = 0; r < 4; ++r) ss[r] += __shfl_xor(ss[r], m, 64);
    }
    float sp[4];
    #pragma unroll
    for (int r = 0; r < 4; ++r) {
        float rn = rsqrtf(ss[r] * (1.0f/HID) + 1e-5f);
        float t = 0.f;
        #pragma unroll
        for (int nt = 0; nt < 8; ++nt)
            t += siluf(acc[nt][r] * rn * g2v[nt]) * w3v[nt];
        sp[r] = t;
    }
    #pragma unroll
    for (int m = 8; m >= 1; m >>= 1) {
        #pragma unroll
        for (int r = 0; r < 4; ++r) sp[r] += __shfl_xor(sp[r], m, 64);
    }
    if (l15 == 0) {
        #pragma unroll
        for (int r = 0; r < 4; ++r)
            sm.sedge[16*wid + lq*4 + r] = sp[r] + b3s;   // edge scalar (b3 folded)
    }
    __syncthreads();                                            // B7

    // ---- final: wave w (w<2) sums node w's 32 edge messages lane-parallel ----
    if (wid < NPB) {
        float mx = 0.f, my = 0.f, mz = 0.f;
        if (lane < KK) {
            int r = sm.recvs[wid][lane];
            float cx = (wid ? px1 : px0) - pos[3*r];
            float cy = (wid ? py1 : py0) - pos[3*r+1];
            float cz = (wid ? pz1 : pz0) - pos[3*r+2];
            float s  = sm.sedge[KK*wid + lane];
            mx = cx * s; my = cy * s; mz = cz * s;
        }
        #pragma unroll
        for (int m = 16; m >= 1; m >>= 1) {
            mx += __shfl_xor(mx, m, 64);
            my += __shfl_xor(my, m, 64);
            mz += __shfl_xor(mz, m, 64);
        }
        if (lane == 0) {
            int node = i0 + wid;
            out[3*node    ] = (wid ? px1 : px0) + mx * (1.0f/KK);
            out[3*node + 1] = (wid ? py1 : py0) + my * (1.0f/KK);
            out[3*node + 2] = (wid ? pz1 : pz0) + mz * (1.0f/KK);
        }
    }
}

extern "C" void kernel_launch(void* const* d_in, const int* in_sizes, int n_in,
                              void* d_out, int out_size, void* d_ws, size_t ws_size,
                              hipStream_t stream) {
    (void)in_sizes; (void)n_in; (void)out_size;
    const float* pos = (const float*)d_in[0];
    const float* t   = (const float*)d_in[1];
    const float* W1  = (const float*)d_in[2];
    const float* b1  = (const float*)d_in[3];
    const float* g1  = (const float*)d_in[4];
    const float* W2  = (const float*)d_in[5];
    const float* b2  = (const float*)d_in[6];
    const float* g2  = (const float*)d_in[7];
    const float* W3  = (const float*)d_in[8];
    const float* b3  = (const float*)d_in[9];
    float* out = (float*)d_out;

    if (d_ws != nullptr && ws_size >= 32768) {
        prepack_w2<<<8, BLK, 0, stream>>>(W2, (uint4*)d_ws);
        egnn_main<true><<<GRID, BLK, 0, stream>>>(
            pos, t, W1, b1, g1, W2, b2, g2, W3, b3, (const uint4*)d_ws, out);
    } else {
        egnn_main<false><<<GRID, BLK, 0, stream>>>(
            pos, t, W1, b1, g1, W2, b2, g2, W3, b3, nullptr, out);
    }
}

// Round 13
// 128.685 us; speedup vs baseline: 1.0481x; 1.0481x over previous
//
#include <hip/hip_runtime.h>
#include <stdint.h>

#define NN   4096
#define KK   32
#define HID  128
#define BLK  256
#define NPB  2
#define GRID (NN / NPB)
#define CAP  128

typedef unsigned short bf16_t;
typedef __attribute__((ext_vector_type(8))) short bf16x8;
typedef __attribute__((ext_vector_type(4))) float f32x4;

#define FINF __uint_as_float(0x7f800000u)

__device__ __forceinline__ bf16_t f2bf(float f) {
    uint32_t u = __float_as_uint(f);
    u = u + 0x7fffu + ((u >> 16) & 1u);   // round-to-nearest-even
    return (bf16_t)(u >> 16);
}
__device__ __forceinline__ float siluf(float x) {
    return x / (1.0f + __expf(-x));
}

// ---- prepack: W2 fp32 -> bf16 in MFMA B-fragment order ----
__global__ __launch_bounds__(BLK) void prepack_w2(
    const float* __restrict__ W2, uint4* __restrict__ w2b)
{
    int c  = blockIdx.x * BLK + threadIdx.x;
    int f  = c >> 6, ln = c & 63;
    int NT = f >> 2, kk = f & 3;
    int row = NT*16 + (ln & 15);
    int k0  = kk*32 + (ln >> 4) * 8;
    const float* s = W2 + row * HID + k0;
    float4 lo = *(const float4*)s;
    float4 hi = *(const float4*)(s + 4);
    uint4 pk;
    pk.x = (uint32_t)f2bf(lo.x) | ((uint32_t)f2bf(lo.y) << 16);
    pk.y = (uint32_t)f2bf(lo.z) | ((uint32_t)f2bf(lo.w) << 16);
    pk.z = (uint32_t)f2bf(hi.x) | ((uint32_t)f2bf(hi.y) << 16);
    pk.w = (uint32_t)f2bf(hi.z) | ((uint32_t)f2bf(hi.w) << 16);
    w2b[c] = pk;
}

template<bool WS>
struct __align__(16) Sm {
    union __align__(16) {                 // phase-disjoint reuse
        uint32_t hist[NPB][1024];         // 8 KB: histogram of SAMPLE MINS only
        ushort h1[64 * HID];              // 16 KB: MLP A-operand, bf16, swizzled
    } u;
    uint32_t w2l[WS ? 4 : HID * 64];      // W2 LDS staging only in fallback
    unsigned long long cand[NPB][CAP];    // 2 KB
    float sedge[64];
    int recvs[NPB][KK];
    int waveTot[NPB][4];
    unsigned long long redk[4];
    uint32_t excl[128];                   // fallback exclusion bitmap (4096 bits)
    int pivotB[NPB];
    int cnt[NPB];
};

template<bool WS>
__global__ __launch_bounds__(BLK) void egnn_main(
    const float* __restrict__ pos, const float* __restrict__ tptr,
    const float* __restrict__ W1,  const float* __restrict__ b1,
    const float* __restrict__ g1,  const float* __restrict__ W2,
    const float* __restrict__ b2,  const float* __restrict__ g2,
    const float* __restrict__ W3,  const float* __restrict__ b3,
    const uint4* __restrict__ w2b, float* __restrict__ out)
{
    __shared__ Sm<WS> sm;
    const int tid  = threadIdx.x;
    const int lane = tid & 63;
    const int wid  = tid >> 6;
    const int bid  = blockIdx.x;
    const int i0   = NPB * bid, i1 = i0 + 1;
    const int l15  = lane & 15, lq = lane >> 4;

    const float ts  = tptr[0];
    const float b3s = b3[0];

    // closed-form RMS coefficients: sum_n (rad*a_n + c_n)^2 = rad^2*A2 + 2*rad*AC + C2
    float A2, AC, C2;
    {
        const float4 w1v = ((const float4*)W1)[lane];     // rows 2l,2l+1
        const float2 b1v = ((const float2*)b1)[lane];
        float t0 = ts * w1v.y + b1v.x;
        float t1 = ts * w1v.w + b1v.y;
        A2 = w1v.x*w1v.x + w1v.z*w1v.z;
        AC = w1v.x*t0    + w1v.z*t1;
        C2 = t0*t0       + t1*t1;
        #pragma unroll
        for (int m = 32; m >= 1; m >>= 1) {
            A2 += __shfl_xor(A2, m, 64);
            AC += __shfl_xor(AC, m, 64);
            C2 += __shfl_xor(C2, m, 64);
        }
    }

    if constexpr (!WS) {
        for (int idx = tid; idx < HID * 16; idx += BLK) {
            int row = idx >> 4, c = idx & 15;
            const float* src = W2 + row * HID + c * 8;
            float4 lo = *(const float4*)src;
            float4 hi = *(const float4*)(src + 4);
            uint4 pk;
            pk.x = (uint32_t)f2bf(lo.x) | ((uint32_t)f2bf(lo.y) << 16);
            pk.y = (uint32_t)f2bf(lo.z) | ((uint32_t)f2bf(lo.w) << 16);
            pk.z = (uint32_t)f2bf(hi.x) | ((uint32_t)f2bf(hi.y) << 16);
            pk.w = (uint32_t)f2bf(hi.z) | ((uint32_t)f2bf(hi.w) << 16);
            *((uint4*)&sm.w2l[row * 64 + 4 * (c ^ (row & 15))]) = pk;
        }
    }
    // zero sample histograms: 2048 dwords = 512 uint4, 2 per thread
    {
        uint4 z = uint4{0u, 0u, 0u, 0u};
        uint4* hz = (uint4*)sm.u.hist;
        hz[tid] = z; hz[tid + 256] = z;
    }
    if (tid == 0) { sm.cnt[0] = 0; sm.cnt[1] = 0; }
    __syncthreads();                                            // B1

    // node centers: pos[6*bid .. +5] as 3x float2
    const float2 c01 = ((const float2*)pos)[3*bid    ];
    const float2 c23 = ((const float2*)pos)[3*bid + 1];
    const float2 c45 = ((const float2*)pos)[3*bid + 2];
    const float px0 = c01.x, py0 = c01.y, pz0 = c23.x;
    const float px1 = c23.y, py1 = c45.x, pz1 = c45.y;

    // ---- pass 1: per-thread SAMPLE MINS only (no distance storage -> no spill) ----
    // thread covers j = 1024*g + 4*tid + c; self excluded inline (d -> inf)
    float m0 = FINF, m1 = FINF;
    {
        const float4* p4 = (const float4*)pos;
        #pragma unroll
        for (int g = 0; g < 4; ++g) {
            float4 f0 = p4[768*g + 3*tid];
            float4 f1 = p4[768*g + 3*tid + 1];
            float4 f2 = p4[768*g + 3*tid + 2];
            float jx[4] = {f0.x, f0.w, f1.z, f2.y};
            float jy[4] = {f0.y, f1.x, f1.w, f2.z};
            float jz[4] = {f0.z, f1.y, f2.x, f2.w};
            #pragma unroll
            for (int c = 0; c < 4; ++c) {
                int j = 1024*g + 4*tid + c;
                float dx0 = px0 - jx[c], dy0 = py0 - jy[c], dz0 = pz0 - jz[c];
                float d0 = __fadd_rn(__fadd_rn(__fmul_rn(dx0,dx0), __fmul_rn(dy0,dy0)),
                                     __fmul_rn(dz0,dz0));
                if (j == i0) d0 = FINF;
                m0 = fminf(m0, d0);
                float dx1 = px1 - jx[c], dy1 = py1 - jy[c], dz1 = pz1 - jz[c];
                float d1 = __fadd_rn(__fadd_rn(__fmul_rn(dx1,dx1), __fmul_rn(dy1,dy1)),
                                     __fmul_rn(dz1,dz1));
                if (j == i1) d1 = FINF;
                m1 = fminf(m1, d1);
            }
        }
    }
    atomicAdd((int*)&sm.u.hist[0][__float_as_uint(m0) >> 21], 1);
    atomicAdd((int*)&sm.u.hist[1][__float_as_uint(m1) >> 21], 1);
    __syncthreads();                                            // B2

    // ---- pivot bucket B: first bucket where cumulative SAMPLE count >= KK ----
    // >=KK sample-mins at distinct j (self excluded) <= UB(B) => v_KK <= UB(B):
    // {j : bucket(d_j) <= B} provably contains the exact top-KK.
    {
        const int b0 = tid * 4;
        uint4 qa = *(const uint4*)&sm.u.hist[0][b0];
        uint4 qb = *(const uint4*)&sm.u.hist[1][b0];
        int a0 = (int)qa.x, a1 = (int)qa.y, a2 = (int)qa.z, a3 = (int)qa.w;
        int e0 = (int)qb.x, e1 = (int)qb.y, e2 = (int)qb.z, e3 = (int)qb.w;
        int s0 = a0+a1+a2+a3, s1 = e0+e1+e2+e3;
        int in0 = s0, in1 = s1;
        #pragma unroll
        for (int off = 1; off < 64; off <<= 1) {
            int v0 = __shfl_up(in0, off, 64);
            int v1 = __shfl_up(in1, off, 64);
            if (lane >= off) { in0 += v0; in1 += v1; }
        }
        if (lane == 63) { sm.waveTot[0][wid] = in0; sm.waveTot[1][wid] = in1; }
        __syncthreads();                                        // B3
        int base0 = 0, base1 = 0;
        for (int w = 0; w < wid; ++w) { base0 += sm.waveTot[0][w]; base1 += sm.waveTot[1][w]; }
        int E0 = base0 + in0 - s0;
        if (E0 < KK && E0 + s0 >= KK) {
            int cum = E0, B = b0 + 3;
            if (cum + a0 >= KK) B = b0;
            else { cum += a0;
                if (cum + a1 >= KK) B = b0 + 1;
                else { cum += a1; if (cum + a2 >= KK) B = b0 + 2; }
            }
            sm.pivotB[0] = B;
        }
        int E1 = base1 + in1 - s1;
        if (E1 < KK && E1 + s1 >= KK) {
            int cum = E1, B = b0 + 3;
            if (cum + e0 >= KK) B = b0;
            else { cum += e0;
                if (cum + e1 >= KK) B = b0 + 1;
                else { cum += e1; if (cum + e2 >= KK) B = b0 + 2; }
            }
            sm.pivotB[1] = B;
        }
    }
    __syncthreads();                                            // B4

    // ---- pass 2: compaction with RECOMPUTED distances (bit-identical chain) ----
    {
        const int B0 = sm.pivotB[0], B1v = sm.pivotB[1];
        const float4* p4 = (const float4*)pos;
        #pragma unroll
        for (int g = 0; g < 4; ++g) {
            float4 f0 = p4[768*g + 3*tid];
            float4 f1 = p4[768*g + 3*tid + 1];
            float4 f2 = p4[768*g + 3*tid + 2];
            float jx[4] = {f0.x, f0.w, f1.z, f2.y};
            float jy[4] = {f0.y, f1.x, f1.w, f2.z};
            float jz[4] = {f0.z, f1.y, f2.x, f2.w};
            #pragma unroll
            for (int c = 0; c < 4; ++c) {
                int j = 1024*g + 4*tid + c;
                float dx0 = px0 - jx[c], dy0 = py0 - jy[c], dz0 = pz0 - jz[c];
                float d0 = __fadd_rn(__fadd_rn(__fmul_rn(dx0,dx0), __fmul_rn(dy0,dy0)),
                                     __fmul_rn(dz0,dz0));
                if (j == i0) d0 = FINF;
                uint32_t ub0 = __float_as_uint(d0);
                if ((int)(ub0 >> 21) <= B0) {
                    int slot = atomicAdd(&sm.cnt[0], 1);
                    if (slot < CAP)
                        sm.cand[0][slot] = (((unsigned long long)ub0) << 12) | (unsigned)j;
                }
                float dx1 = px1 - jx[c], dy1 = py1 - jy[c], dz1 = pz1 - jz[c];
                float d1 = __fadd_rn(__fadd_rn(__fmul_rn(dx1,dx1), __fmul_rn(dy1,dy1)),
                                     __fmul_rn(dz1,dz1));
                if (j == i1) d1 = FINF;
                uint32_t ub1 = __float_as_uint(d1);
                if ((int)(ub1 >> 21) <= B1v) {
                    int slot = atomicAdd(&sm.cnt[1], 1);
                    if (slot < CAP)
                        sm.cand[1][slot] = (((unsigned long long)ub1) << 12) | (unsigned)j;
                }
            }
        }
    }
    __syncthreads();                                            // B5

    const int c0 = sm.cnt[0], c1v = sm.cnt[1];
    if (c0 <= CAP && c1v <= CAP) {
        // threads 0..127 rank node0 cands; 128..255 rank node1
        int nn = tid >> 7, tt = tid & 127;
        int cN = nn ? c1v : c0;
        if (tt < cN) {
            unsigned long long km = sm.cand[nn][tt];
            int rank = 0;
            for (int q = 0; q < cN; ++q)
                rank += (sm.cand[nn][q] < km) ? 1 : 0;
            if (rank < KK) sm.recvs[nn][rank] = (int)(km & 0xFFFull);
        }
    } else {
        // cold fallback (overflow; ~never): recompute argmin w/ exclusion bitmap
        for (int nn = 0; nn < NPB; ++nn) {
            if (tid < 128) sm.excl[tid] = 0u;
            __syncthreads();
            const int   iself = nn ? i1 : i0;
            const float pxn = nn ? px1 : px0;
            const float pyn = nn ? py1 : py0;
            const float pzn = nn ? pz1 : pz0;
            for (int it = 0; it < KK; ++it) {
                unsigned long long best = ~0ull;
                const float4* p4 = (const float4*)pos;
                for (int g = 0; g < 4; ++g) {
                    float4 f0 = p4[768*g + 3*tid];
                    float4 f1 = p4[768*g + 3*tid + 1];
                    float4 f2 = p4[768*g + 3*tid + 2];
                    float jx[4] = {f0.x, f0.w, f1.z, f2.y};
                    float jy[4] = {f0.y, f1.x, f1.w, f2.z};
                    float jz[4] = {f0.z, f1.y, f2.x, f2.w};
                    for (int c = 0; c < 4; ++c) {
                        int j = 1024*g + 4*tid + c;
                        float dx = pxn - jx[c], dy = pyn - jy[c], dz = pzn - jz[c];
                        float d = __fadd_rn(__fadd_rn(__fmul_rn(dx,dx), __fmul_rn(dy,dy)),
                                            __fmul_rn(dz,dz));
                        bool dead = (j == iself) || ((sm.excl[j >> 5] >> (j & 31)) & 1u);
                        unsigned long long key = dead ? ~0ull
                            : ((((unsigned long long)__float_as_uint(d)) << 12) | (unsigned)j);
                        best = best < key ? best : key;
                    }
                }
                #pragma unroll
                for (int m = 32; m >= 1; m >>= 1) {
                    unsigned long long o = __shfl_xor(best, m, 64);
                    best = best < o ? best : o;
                }
                if (lane == 0) sm.redk[wid] = best;
                __syncthreads();
                if (tid == 0) {
                    unsigned long long b01 = sm.redk[0] < sm.redk[1] ? sm.redk[0] : sm.redk[1];
                    unsigned long long b23 = sm.redk[2] < sm.redk[3] ? sm.redk[2] : sm.redk[3];
                    unsigned long long b   = b01 < b23 ? b01 : b23;
                    int j = (int)(b & 0xfffull);
                    sm.recvs[nn][it] = j;
                    atomicOr((unsigned int*)&sm.excl[j >> 5], 1u << (j & 31));
                }
                __syncthreads();
            }
        }
    }
    __syncthreads();                                            // B6

    // ---- layer 1 fused with edge gather; writes wave-local h1 rows as b128 ----
    {
        const int ch = lane >> 2, epr = lane & 3;
        float4 wA = ((const float4*)W1)[ch*4    ];
        float4 wB = ((const float4*)W1)[ch*4 + 1];
        float4 wC = ((const float4*)W1)[ch*4 + 2];
        float4 wD = ((const float4*)W1)[ch*4 + 3];
        float4 bA = ((const float4*)b1)[ch*2], bB = ((const float4*)b1)[ch*2 + 1];
        float4 gA = ((const float4*)g1)[ch*2], gB = ((const float4*)g1)[ch*2 + 1];
        float av[8] = {wA.x, wA.z, wB.x, wB.z, wC.x, wC.z, wD.x, wD.z};
        float cv[8] = {ts*wA.y + bA.x, ts*wA.w + bA.y, ts*wB.y + bA.z, ts*wB.w + bA.w,
                       ts*wC.y + bB.x, ts*wC.w + bB.y, ts*wD.y + bB.z, ts*wD.w + bB.w};
        float gv[8] = {gA.x, gA.y, gA.z, gA.w, gB.x, gB.y, gB.z, gB.w};

        const int nodeW = wid >> 1;
        const float pxw = nodeW ? px1 : px0;
        const float pyw = nodeW ? py1 : py0;
        const float pzw = nodeW ? pz1 : pz0;
        uint4* h1q = (uint4*)sm.u.h1;
        #pragma unroll
        for (int g = 0; g < 4; ++g) {
            int E = 16*wid + 4*g + epr;
            int r = sm.recvs[nodeW][E & 31];
            float dx = pxw - pos[3*r];
            float dy = pyw - pos[3*r+1];
            float dz = pzw - pos[3*r+2];
            float rad = __fadd_rn(__fadd_rn(__fmul_rn(dx,dx), __fmul_rn(dy,dy)),
                                  __fmul_rn(dz,dz));
            float sqv = rad*rad*A2 + 2.0f*rad*AC + C2;
            float rn  = rsqrtf(sqv * (1.0f/HID) + 1e-5f);
            uint32_t pk[4];
            #pragma unroll
            for (int p = 0; p < 4; ++p) {
                float va = siluf((rad*av[2*p]   + cv[2*p])   * rn * gv[2*p]);
                float vb = siluf((rad*av[2*p+1] + cv[2*p+1]) * rn * gv[2*p+1]);
                pk[p] = (__float_as_uint(va) >> 16) | (__float_as_uint(vb) & 0xffff0000u);
            }
            h1q[E*16 + (ch ^ (E & 15))] = uint4{pk[0], pk[1], pk[2], pk[3]};
        }
    }
    // no barrier: h1 rows [16w,16w+16) are written and read only by wave w

    // ---- layer 2 via MFMA: wave w = m-tile w (16 edges), ALL 8 n-tiles ----
    f32x4 acc[8];
    #pragma unroll
    for (int nt = 0; nt < 8; ++nt) acc[nt] = f32x4{0.f, 0.f, 0.f, 0.f};
    {
        const bf16x8* h1v = (const bf16x8*)sm.u.h1;   // [64][16 chunks]
        const int m = 16*wid + l15;
        if constexpr (WS) {
            const bf16x8* bv = (const bf16x8*)w2b;
            #pragma unroll
            for (int kk = 0; kk < 4; ++kk) {
                bf16x8 af = h1v[m*16 + ((kk*4 + lq) ^ l15)];
                #pragma unroll
                for (int nt = 0; nt < 8; ++nt)
                    acc[nt] = __builtin_amdgcn_mfma_f32_16x16x32_bf16(
                                  af, bv[(nt*4 + kk)*64 + lane], acc[nt], 0, 0, 0);
            }
        } else {
            const bf16x8* w2v = (const bf16x8*)sm.w2l;    // [128][16 chunks]
            #pragma unroll
            for (int kk = 0; kk < 4; ++kk) {
                const int q = (kk*4 + lq) ^ l15;
                bf16x8 af = h1v[m*16 + q];
                #pragma unroll
                for (int nt = 0; nt < 8; ++nt)
                    acc[nt] = __builtin_amdgcn_mfma_f32_16x16x32_bf16(
                                  af, w2v[(nt*16 + l15)*16 + q], acc[nt], 0, 0, 0);
            }
        }
    }

    // ---- epilogue (fully wave-local): n = nt*16 + l15 ----
    float g2v[8], w3v[8], b2v[8];
    #pragma unroll
    for (int nt = 0; nt < 8; ++nt) {
        int n = nt*16 + l15;
        g2v[nt] = g2[n]; w3v[nt] = W3[n]; b2v[nt] = b2[n];
    }
    float ss[4];
    #pragma unroll
    for (int r = 0; r < 4; ++r) {
        float t = 0.f;
        #pragma unroll
        for (int nt = 0; nt < 8; ++nt) {
            float zz = acc[nt][r] + b2v[nt];
            acc[nt][r] = zz;
            t += zz*zz;
        }
        ss[r] = t;
    }
    #pragma unroll
    for (int m = 8; m >= 1; m >>= 1) {
        #pragma unroll
        for (int r = 0; r < 4; ++r) ss[r] += __shfl_xor(ss[r], m, 64);
    }
    float sp[4];
    #pragma unroll
    for (int r = 0; r < 4; ++r) {
        float rn = rsqrtf(ss[r] * (1.0f/HID) + 1e-5f);
        float t = 0.f;
        #pragma unroll
        for (int nt = 0; nt < 8; ++nt)
            t += siluf(acc[nt][r] * rn * g2v[nt]) * w3v[nt];
        sp[r] = t;
    }
    #pragma unroll
    for (int m = 8; m >= 1; m >>= 1) {
        #pragma unroll
        for (int r = 0; r < 4; ++r) sp[r] += __shfl_xor(sp[r], m, 64);
    }
    if (l15 == 0) {
        #pragma unroll
        for (int r = 0; r < 4; ++r)
            sm.sedge[16*wid + lq*4 + r] = sp[r] + b3s;   // edge scalar (b3 folded)
    }
    __syncthreads();                                            // B7

    // ---- final: wave w (w<2) sums node w's 32 edge messages lane-parallel ----
    if (wid < NPB) {
        float mx = 0.f, my = 0.f, mz = 0.f;
        if (lane < KK) {
            int r = sm.recvs[wid][lane];
            float cx = (wid ? px1 : px0) - pos[3*r];
            float cy = (wid ? py1 : py0) - pos[3*r+1];
            float cz = (wid ? pz1 : pz0) - pos[3*r+2];
            float s  = sm.sedge[KK*wid + lane];
            mx = cx * s; my = cy * s; mz = cz * s;
        }
        #pragma unroll
        for (int m = 16; m >= 1; m >>= 1) {
            mx += __shfl_xor(mx, m, 64);
            my += __shfl_xor(my, m, 64);
            mz += __shfl_xor(mz, m, 64);
        }
        if (lane == 0) {
            int node = i0 + wid;
            out[3*node    ] = (wid ? px1 : px0) + mx * (1.0f/KK);
            out[3*node + 1] = (wid ? py1 : py0) + my * (1.0f/KK);
            out[3*node + 2] = (wid ? pz1 : pz0) + mz * (1.0f/KK);
        }
    }
}

extern "C" void kernel_launch(void* const* d_in, const int* in_sizes, int n_in,
                              void* d_out, int out_size, void* d_ws, size_t ws_size,
                              hipStream_t stream) {
    (void)in_sizes; (void)n_in; (void)out_size;
    const float* pos = (const float*)d_in[0];
    const float* t   = (const float*)d_in[1];
    const float* W1  = (const float*)d_in[2];
    const float* b1  = (const float*)d_in[3];
    const float* g1  = (const float*)d_in[4];
    const float* W2  = (const float*)d_in[5];
    const float* b2  = (const float*)d_in[6];
    const float* g2  = (const float*)d_in[7];
    const float* W3  = (const float*)d_in[8];
    const float* b3  = (const float*)d_in[9];
    float* out = (float*)d_out;

    if (d_ws != nullptr && ws_size >= 32768) {
        prepack_w2<<<8, BLK, 0, stream>>>(W2, (uint4*)d_ws);
        egnn_main<true><<<GRID, BLK, 0, stream>>>(
            pos, t, W1, b1, g1, W2, b2, g2, W3, b3, (const uint4*)d_ws, out);
    } else {
        egnn_main<false><<<GRID, BLK, 0, stream>>>(
            pos, t, W1, b1, g1, W2, b2, g2, W3, b3, nullptr, out);
    }
}

// Round 14
// 127.371 us; speedup vs baseline: 1.0589x; 1.0103x over previous
//
#include <hip/hip_runtime.h>
#include <stdint.h>

#define NN   4096
#define KK   32
#define HID  128
#define BLK  256
#define NPB  2
#define GRID (NN / NPB)
#define CAP  128

typedef unsigned short bf16_t;
typedef __attribute__((ext_vector_type(8))) short bf16x8;
typedef __attribute__((ext_vector_type(4))) float f32x4;

#define FINF __uint_as_float(0x7f800000u)

__device__ __forceinline__ bf16_t f2bf(float f) {
    uint32_t u = __float_as_uint(f);
    u = u + 0x7fffu + ((u >> 16) & 1u);   // round-to-nearest-even
    return (bf16_t)(u >> 16);
}
__device__ __forceinline__ float siluf(float x) {
    return x / (1.0f + __expf(-x));
}

// ---- prepack: W2 fp32 -> bf16 in MFMA B-fragment order ----
__global__ __launch_bounds__(BLK) void prepack_w2(
    const float* __restrict__ W2, uint4* __restrict__ w2b)
{
    int c  = blockIdx.x * BLK + threadIdx.x;
    int f  = c >> 6, ln = c & 63;
    int NT = f >> 2, kk = f & 3;
    int row = NT*16 + (ln & 15);
    int k0  = kk*32 + (ln >> 4) * 8;
    const float* s = W2 + row * HID + k0;
    float4 lo = *(const float4*)s;
    float4 hi = *(const float4*)(s + 4);
    uint4 pk;
    pk.x = (uint32_t)f2bf(lo.x) | ((uint32_t)f2bf(lo.y) << 16);
    pk.y = (uint32_t)f2bf(lo.z) | ((uint32_t)f2bf(lo.w) << 16);
    pk.z = (uint32_t)f2bf(hi.x) | ((uint32_t)f2bf(hi.y) << 16);
    pk.w = (uint32_t)f2bf(hi.z) | ((uint32_t)f2bf(hi.w) << 16);
    w2b[c] = pk;
}

template<bool WS>
struct __align__(16) Sm {
    union __align__(16) {                 // phase-disjoint reuse (24 KB)
        struct {
            ushort   dbf[NPB][NN];        // 16 KB: top-16 distance bits per j
            uint32_t hist[NPB][1024];     //  8 KB: sample-min histogram
        } sel;
        ushort h1[64 * HID];              // 16 KB: MLP A-operand, bf16, swizzled
    } u;
    uint32_t w2l[WS ? 4 : HID * 64];      // W2 LDS staging only in fallback
    uint32_t cand[NPB][CAP];              // 1 KB: (d16<<16)|j keys
    float sedge[64];
    int recvs[NPB][KK];
    int waveTot[NPB][4];
    unsigned long long redk[4];
    uint32_t excl[128];                   // fallback exclusion bitmap
    int pivotB[NPB];
    int cnt[NPB];
};

template<bool WS>
__global__ __launch_bounds__(BLK) void egnn_main(
    const float* __restrict__ pos, const float* __restrict__ tptr,
    const float* __restrict__ W1,  const float* __restrict__ b1,
    const float* __restrict__ g1,  const float* __restrict__ W2,
    const float* __restrict__ b2,  const float* __restrict__ g2,
    const float* __restrict__ W3,  const float* __restrict__ b3,
    const uint4* __restrict__ w2b, float* __restrict__ out)
{
    __shared__ Sm<WS> sm;
    const int tid  = threadIdx.x;
    const int lane = tid & 63;
    const int wid  = tid >> 6;
    const int bid  = blockIdx.x;
    const int i0   = NPB * bid, i1 = i0 + 1;
    const int l15  = lane & 15, lq = lane >> 4;

    const float ts  = tptr[0];
    const float b3s = b3[0];

    // closed-form RMS coefficients: sum_n (rad*a_n + c_n)^2 = rad^2*A2 + 2*rad*AC + C2
    float A2, AC, C2;
    {
        const float4 w1v = ((const float4*)W1)[lane];     // rows 2l,2l+1
        const float2 b1v = ((const float2*)b1)[lane];
        float t0 = ts * w1v.y + b1v.x;
        float t1 = ts * w1v.w + b1v.y;
        A2 = w1v.x*w1v.x + w1v.z*w1v.z;
        AC = w1v.x*t0    + w1v.z*t1;
        C2 = t0*t0       + t1*t1;
        #pragma unroll
        for (int m = 32; m >= 1; m >>= 1) {
            A2 += __shfl_xor(A2, m, 64);
            AC += __shfl_xor(AC, m, 64);
            C2 += __shfl_xor(C2, m, 64);
        }
    }

    if constexpr (!WS) {
        for (int idx = tid; idx < HID * 16; idx += BLK) {
            int row = idx >> 4, c = idx & 15;
            const float* src = W2 + row * HID + c * 8;
            float4 lo = *(const float4*)src;
            float4 hi = *(const float4*)(src + 4);
            uint4 pk;
            pk.x = (uint32_t)f2bf(lo.x) | ((uint32_t)f2bf(lo.y) << 16);
            pk.y = (uint32_t)f2bf(lo.z) | ((uint32_t)f2bf(lo.w) << 16);
            pk.z = (uint32_t)f2bf(hi.x) | ((uint32_t)f2bf(hi.y) << 16);
            pk.w = (uint32_t)f2bf(hi.z) | ((uint32_t)f2bf(hi.w) << 16);
            *((uint4*)&sm.w2l[row * 64 + 4 * (c ^ (row & 15))]) = pk;
        }
    }
    // zero sample histograms: 2048 dwords = 512 uint4, 2 per thread
    {
        uint4 z = uint4{0u, 0u, 0u, 0u};
        uint4* hz = (uint4*)sm.u.sel.hist;
        hz[tid] = z; hz[tid + 256] = z;
    }
    if (tid == 0) { sm.cnt[0] = 0; sm.cnt[1] = 0; }
    __syncthreads();                                            // B1

    // node centers: pos[6*bid .. +5] as 3x float2
    const float2 c01 = ((const float2*)pos)[3*bid    ];
    const float2 c23 = ((const float2*)pos)[3*bid + 1];
    const float2 c45 = ((const float2*)pos)[3*bid + 2];
    const float px0 = c01.x, py0 = c01.y, pz0 = c23.x;
    const float px1 = c23.y, py1 = c45.x, pz1 = c45.y;

    // ---- pass 1: sample mins + top-16 distance bits to LDS (no spill, no recompute)
    float m0 = FINF, m1 = FINF;
    {
        const float4* p4 = (const float4*)pos;
        #pragma unroll
        for (int g = 0; g < 4; ++g) {
            float4 f0 = p4[768*g + 3*tid];
            float4 f1 = p4[768*g + 3*tid + 1];
            float4 f2 = p4[768*g + 3*tid + 2];
            float jx[4] = {f0.x, f0.w, f1.z, f2.y};
            float jy[4] = {f0.y, f1.x, f1.w, f2.z};
            float jz[4] = {f0.z, f1.y, f2.x, f2.w};
            uint32_t lo0 = 0, hi0 = 0, lo1 = 0, hi1 = 0;
            #pragma unroll
            for (int c = 0; c < 4; ++c) {
                int j = 1024*g + 4*tid + c;
                float dx0 = px0 - jx[c], dy0 = py0 - jy[c], dz0 = pz0 - jz[c];
                float d0 = __fadd_rn(__fadd_rn(__fmul_rn(dx0,dx0), __fmul_rn(dy0,dy0)),
                                     __fmul_rn(dz0,dz0));
                if (j == i0) d0 = FINF;
                m0 = fminf(m0, d0);
                uint32_t t0 = __float_as_uint(d0) >> 16;
                float dx1 = px1 - jx[c], dy1 = py1 - jy[c], dz1 = pz1 - jz[c];
                float d1 = __fadd_rn(__fadd_rn(__fmul_rn(dx1,dx1), __fmul_rn(dy1,dy1)),
                                     __fmul_rn(dz1,dz1));
                if (j == i1) d1 = FINF;
                m1 = fminf(m1, d1);
                uint32_t t1 = __float_as_uint(d1) >> 16;
                if (c < 2) { lo0 |= t0 << (16*c);     lo1 |= t1 << (16*c); }
                else       { hi0 |= t0 << (16*(c-2)); hi1 |= t1 << (16*(c-2)); }
            }
            *((uint2*)&sm.u.sel.dbf[0][1024*g + 4*tid]) = make_uint2(lo0, hi0);
            *((uint2*)&sm.u.sel.dbf[1][1024*g + 4*tid]) = make_uint2(lo1, hi1);
        }
    }
    atomicAdd((int*)&sm.u.sel.hist[0][__float_as_uint(m0) >> 21], 1);
    atomicAdd((int*)&sm.u.sel.hist[1][__float_as_uint(m1) >> 21], 1);
    __syncthreads();                                            // B2

    // ---- pivot bucket B: first bucket where cumulative SAMPLE count >= KK ----
    // >=KK sample-mins at distinct j (self excluded) <= UB(B) => v_KK <= UB(B):
    // {j : bucket(d_j) <= B} provably contains the exact top-KK. bucket is the
    // top-11 bits, preserved exactly by the 16-bit truncation.
    {
        const int b0 = tid * 4;
        uint4 qa = *(const uint4*)&sm.u.sel.hist[0][b0];
        uint4 qb = *(const uint4*)&sm.u.sel.hist[1][b0];
        int a0 = (int)qa.x, a1 = (int)qa.y, a2 = (int)qa.z, a3 = (int)qa.w;
        int e0 = (int)qb.x, e1 = (int)qb.y, e2 = (int)qb.z, e3 = (int)qb.w;
        int s0 = a0+a1+a2+a3, s1 = e0+e1+e2+e3;
        int in0 = s0, in1 = s1;
        #pragma unroll
        for (int off = 1; off < 64; off <<= 1) {
            int v0 = __shfl_up(in0, off, 64);
            int v1 = __shfl_up(in1, off, 64);
            if (lane >= off) { in0 += v0; in1 += v1; }
        }
        if (lane == 63) { sm.waveTot[0][wid] = in0; sm.waveTot[1][wid] = in1; }
        __syncthreads();                                        // B3
        int base0 = 0, base1 = 0;
        for (int w = 0; w < wid; ++w) { base0 += sm.waveTot[0][w]; base1 += sm.waveTot[1][w]; }
        int E0 = base0 + in0 - s0;
        if (E0 < KK && E0 + s0 >= KK) {
            int cum = E0, B = b0 + 3;
            if (cum + a0 >= KK) B = b0;
            else { cum += a0;
                if (cum + a1 >= KK) B = b0 + 1;
                else { cum += a1; if (cum + a2 >= KK) B = b0 + 2; }
            }
            sm.pivotB[0] = B;
        }
        int E1 = base1 + in1 - s1;
        if (E1 < KK && E1 + s1 >= KK) {
            int cum = E1, B = b0 + 3;
            if (cum + e0 >= KK) B = b0;
            else { cum += e0;
                if (cum + e1 >= KK) B = b0 + 1;
                else { cum += e1; if (cum + e2 >= KK) B = b0 + 2; }
            }
            sm.pivotB[1] = B;
        }
    }
    __syncthreads();                                            // B4

    // ---- pass 2: compaction from LDS d16 (no recompute); key = (d16<<16)|j ----
    {
        const int B0 = sm.pivotB[0], B1v = sm.pivotB[1];
        #pragma unroll
        for (int g = 0; g < 4; ++g) {
            uint2 v0 = *((const uint2*)&sm.u.sel.dbf[0][1024*g + 4*tid]);
            uint2 v1 = *((const uint2*)&sm.u.sel.dbf[1][1024*g + 4*tid]);
            uint32_t d16a[4] = {v0.x & 0xffffu, v0.x >> 16, v0.y & 0xffffu, v0.y >> 16};
            uint32_t d16b[4] = {v1.x & 0xffffu, v1.x >> 16, v1.y & 0xffffu, v1.y >> 16};
            #pragma unroll
            for (int c = 0; c < 4; ++c) {
                int j = 1024*g + 4*tid + c;
                if ((int)(d16a[c] >> 5) <= B0) {
                    int slot = atomicAdd(&sm.cnt[0], 1);
                    if (slot < CAP) sm.cand[0][slot] = (d16a[c] << 16) | (unsigned)j;
                }
                if ((int)(d16b[c] >> 5) <= B1v) {
                    int slot = atomicAdd(&sm.cnt[1], 1);
                    if (slot < CAP) sm.cand[1][slot] = (d16b[c] << 16) | (unsigned)j;
                }
            }
        }
    }
    __syncthreads();                                            // B5

    const int c0 = sm.cnt[0], c1v = sm.cnt[1];
    if (c0 <= CAP && c1v <= CAP) {
        // threads 0..127 rank node0 cands; 128..255 rank node1 (x4 unrolled reads)
        int nn = tid >> 7, tt = tid & 127;
        int cN = nn ? c1v : c0;
        if (tt < cN) {
            uint32_t km = sm.cand[nn][tt];
            int rank = 0;
            for (int q = 0; q < cN; q += 4) {
                uint4 v = *((const uint4*)&sm.cand[nn][q]);
                rank += (q     < cN && v.x < km) ? 1 : 0;
                rank += (q + 1 < cN && v.y < km) ? 1 : 0;
                rank += (q + 2 < cN && v.z < km) ? 1 : 0;
                rank += (q + 3 < cN && v.w < km) ? 1 : 0;
            }
            if (rank < KK) sm.recvs[nn][rank] = (int)(km & 0xFFFFu);
        }
    } else {
        // cold fallback (overflow; ~never): recompute argmin w/ exclusion bitmap
        for (int nn = 0; nn < NPB; ++nn) {
            if (tid < 128) sm.excl[tid] = 0u;
            __syncthreads();
            const int   iself = nn ? i1 : i0;
            const float pxn = nn ? px1 : px0;
            const float pyn = nn ? py1 : py0;
            const float pzn = nn ? pz1 : pz0;
            for (int it = 0; it < KK; ++it) {
                unsigned long long best = ~0ull;
                const float4* p4 = (const float4*)pos;
                for (int g = 0; g < 4; ++g) {
                    float4 f0 = p4[768*g + 3*tid];
                    float4 f1 = p4[768*g + 3*tid + 1];
                    float4 f2 = p4[768*g + 3*tid + 2];
                    float jx[4] = {f0.x, f0.w, f1.z, f2.y};
                    float jy[4] = {f0.y, f1.x, f1.w, f2.z};
                    float jz[4] = {f0.z, f1.y, f2.x, f2.w};
                    for (int c = 0; c < 4; ++c) {
                        int j = 1024*g + 4*tid + c;
                        float dx = pxn - jx[c], dy = pyn - jy[c], dz = pzn - jz[c];
                        float d = __fadd_rn(__fadd_rn(__fmul_rn(dx,dx), __fmul_rn(dy,dy)),
                                            __fmul_rn(dz,dz));
                        bool dead = (j == iself) || ((sm.excl[j >> 5] >> (j & 31)) & 1u);
                        unsigned long long key = dead ? ~0ull
                            : ((((unsigned long long)__float_as_uint(d)) << 12) | (unsigned)j);
                        best = best < key ? best : key;
                    }
                }
                #pragma unroll
                for (int m = 32; m >= 1; m >>= 1) {
                    unsigned long long o = __shfl_xor(best, m, 64);
                    best = best < o ? best : o;
                }
                if (lane == 0) sm.redk[wid] = best;
                __syncthreads();
                if (tid == 0) {
                    unsigned long long b01 = sm.redk[0] < sm.redk[1] ? sm.redk[0] : sm.redk[1];
                    unsigned long long b23 = sm.redk[2] < sm.redk[3] ? sm.redk[2] : sm.redk[3];
                    unsigned long long b   = b01 < b23 ? b01 : b23;
                    int j = (int)(b & 0xfffull);
                    sm.recvs[nn][it] = j;
                    atomicOr((unsigned int*)&sm.excl[j >> 5], 1u << (j & 31));
                }
                __syncthreads();
            }
        }
    }
    __syncthreads();                                            // B6

    // ---- layer 1 fused with edge gather; writes wave-local h1 rows as b128 ----
    {
        const int ch = lane >> 2, epr = lane & 3;
        float4 wA = ((const float4*)W1)[ch*4    ];
        float4 wB = ((const float4*)W1)[ch*4 + 1];
        float4 wC = ((const float4*)W1)[ch*4 + 2];
        float4 wD = ((const float4*)W1)[ch*4 + 3];
        float4 bA = ((const float4*)b1)[ch*2], bB = ((const float4*)b1)[ch*2 + 1];
        float4 gA = ((const float4*)g1)[ch*2], gB = ((const float4*)g1)[ch*2 + 1];
        float av[8] = {wA.x, wA.z, wB.x, wB.z, wC.x, wC.z, wD.x, wD.z};
        float cv[8] = {ts*wA.y + bA.x, ts*wA.w + bA.y, ts*wB.y + bA.z, ts*wB.w + bA.w,
                       ts*wC.y + bB.x, ts*wC.w + bB.y, ts*wD.y + bB.z, ts*wD.w + bB.w};
        float gv[8] = {gA.x, gA.y, gA.z, gA.w, gB.x, gB.y, gB.z, gB.w};

        const int nodeW = wid >> 1;
        const float pxw = nodeW ? px1 : px0;
        const float pyw = nodeW ? py1 : py0;
        const float pzw = nodeW ? pz1 : pz0;
        uint4* h1q = (uint4*)sm.u.h1;
        #pragma unroll
        for (int g = 0; g < 4; ++g) {
            int E = 16*wid + 4*g + epr;
            int r = sm.recvs[nodeW][E & 31];
            float dx = pxw - pos[3*r];
            float dy = pyw - pos[3*r+1];
            float dz = pzw - pos[3*r+2];
            float rad = __fadd_rn(__fadd_rn(__fmul_rn(dx,dx), __fmul_rn(dy,dy)),
                                  __fmul_rn(dz,dz));
            float sqv = rad*rad*A2 + 2.0f*rad*AC + C2;
            float rn  = rsqrtf(sqv * (1.0f/HID) + 1e-5f);
            uint32_t pk[4];
            #pragma unroll
            for (int p = 0; p < 4; ++p) {
                float va = siluf((rad*av[2*p]   + cv[2*p])   * rn * gv[2*p]);
                float vb = siluf((rad*av[2*p+1] + cv[2*p+1]) * rn * gv[2*p+1]);
                pk[p] = (__float_as_uint(va) >> 16) | (__float_as_uint(vb) & 0xffff0000u);
            }
            h1q[E*16 + (ch ^ (E & 15))] = uint4{pk[0], pk[1], pk[2], pk[3]};
        }
    }
    // no barrier: h1 rows [16w,16w+16) are written and read only by wave w

    // ---- layer 2 via MFMA: wave w = m-tile w (16 edges), ALL 8 n-tiles ----
    f32x4 acc[8];
    #pragma unroll
    for (int nt = 0; nt < 8; ++nt) acc[nt] = f32x4{0.f, 0.f, 0.f, 0.f};
    {
        const bf16x8* h1v = (const bf16x8*)sm.u.h1;   // [64][16 chunks]
        const int m = 16*wid + l15;
        if constexpr (WS) {
            const bf16x8* bv = (const bf16x8*)w2b;
            #pragma unroll
            for (int kk = 0; kk < 4; ++kk) {
                bf16x8 af = h1v[m*16 + ((kk*4 + lq) ^ l15)];
                #pragma unroll
                for (int nt = 0; nt < 8; ++nt)
                    acc[nt] = __builtin_amdgcn_mfma_f32_16x16x32_bf16(
                                  af, bv[(nt*4 + kk)*64 + lane], acc[nt], 0, 0, 0);
            }
        } else {
            const bf16x8* w2v = (const bf16x8*)sm.w2l;    // [128][16 chunks]
            #pragma unroll
            for (int kk = 0; kk < 4; ++kk) {
                const int q = (kk*4 + lq) ^ l15;
                bf16x8 af = h1v[m*16 + q];
                #pragma unroll
                for (int nt = 0; nt < 8; ++nt)
                    acc[nt] = __builtin_amdgcn_mfma_f32_16x16x32_bf16(
                                  af, w2v[(nt*16 + l15)*16 + q], acc[nt], 0, 0, 0);
            }
        }
    }

    // ---- epilogue (fully wave-local): n = nt*16 + l15 ----
    float g2v[8], w3v[8], b2v[8];
    #pragma unroll
    for (int nt = 0; nt < 8; ++nt) {
        int n = nt*16 + l15;
        g2v[nt] = g2[n]; w3v[nt] = W3[n]; b2v[nt] = b2[n];
    }
    float ss[4];
    #pragma unroll
    for (int r = 0; r < 4; ++r) {
        float t = 0.f;
        #pragma unroll
        for (int nt = 0; nt < 8; ++nt) {
            float zz = acc[nt][r] + b2v[nt];
            acc[nt][r] = zz;
            t += zz*zz;
        }
        ss[r] = t;
    }
    #pragma unroll
    for (int m = 8; m >= 1; m >>= 1) {
        #pragma unroll
        for (int r = 0; r < 4; ++r) ss[r] += __shfl_xor(ss[r], m, 64);
    }
    float sp[4];
    #pragma unroll
    for (int r = 0; r < 4; ++r) {
        float rn = rsqrtf(ss[r] * (1.0f/HID) + 1e-5f);
        float t = 0.f;
        #pragma unroll
        for (int nt = 0; nt < 8; ++nt)
            t += siluf(acc[nt][r] * rn * g2v[nt]) * w3v[nt];
        sp[r] = t;
    }
    #pragma unroll
    for (int m = 8; m >= 1; m >>= 1) {
        #pragma unroll
        for (int r = 0; r < 4; ++r) sp[r] += __shfl_xor(sp[r], m, 64);
    }
    if (l15 == 0) {
        #pragma unroll
        for (int r = 0; r < 4; ++r)
            sm.sedge[16*wid + lq*4 + r] = sp[r] + b3s;   // edge scalar (b3 folded)
    }
    __syncthreads();                                            // B7

    // ---- final: wave w (w<2) sums node w's 32 edge messages lane-parallel ----
    if (wid < NPB) {
        float mx = 0.f, my = 0.f, mz = 0.f;
        if (lane < KK) {
            int r = sm.recvs[wid][lane];
            float cx = (wid ? px1 : px0) - pos[3*r];
            float cy = (wid ? py1 : py0) - pos[3*r+1];
            float cz = (wid ? pz1 : pz0) - pos[3*r+2];
            float s  = sm.sedge[KK*wid + lane];
            mx = cx * s; my = cy * s; mz = cz * s;
        }
        #pragma unroll
        for (int m = 16; m >= 1; m >>= 1) {
            mx += __shfl_xor(mx, m, 64);
            my += __shfl_xor(my, m, 64);
            mz += __shfl_xor(mz, m, 64);
        }
        if (lane == 0) {
            int node = i0 + wid;
            out[3*node    ] = (wid ? px1 : px0) + mx * (1.0f/KK);
            out[3*node + 1] = (wid ? py1 : py0) + my * (1.0f/KK);
            out[3*node + 2] = (wid ? pz1 : pz0) + mz * (1.0f/KK);
        }
    }
}

extern "C" void kernel_launch(void* const* d_in, const int* in_sizes, int n_in,
                              void* d_out, int out_size, void* d_ws, size_t ws_size,
                              hipStream_t stream) {
    (void)in_sizes; (void)n_in; (void)out_size;
    const float* pos = (const float*)d_in[0];
    const float* t   = (const float*)d_in[1];
    const float* W1  = (const float*)d_in[2];
    const float* b1  = (const float*)d_in[3];
    const float* g1  = (const float*)d_in[4];
    const float* W2  = (const float*)d_in[5];
    const float* b2  = (const float*)d_in[6];
    const float* g2  = (const float*)d_in[7];
    const float* W3  = (const float*)d_in[8];
    const float* b3  = (const float*)d_in[9];
    float* out = (float*)d_out;

    if (d_ws != nullptr && ws_size >= 32768) {
        prepack_w2<<<8, BLK, 0, stream>>>(W2, (uint4*)d_ws);
        egnn_main<true><<<GRID, BLK, 0, stream>>>(
            pos, t, W1, b1, g1, W2, b2, g2, W3, b3, (const uint4*)d_ws, out);
    } else {
        egnn_main<false><<<GRID, BLK, 0, stream>>>(
            pos, t, W1, b1, g1, W2, b2, g2, W3, b3, nullptr, out);
    }
}

// Round 15
// 123.918 us; speedup vs baseline: 1.0884x; 1.0279x over previous
//
#include <hip/hip_runtime.h>
#include <stdint.h>

#define NN   4096
#define KK   32
#define HID  128
#define BLK  512
#define NPB  2
#define GRID (NN / NPB)
#define CAP  128

typedef unsigned short bf16_t;
typedef __attribute__((ext_vector_type(8))) short bf16x8;
typedef __attribute__((ext_vector_type(4))) float f32x4;

#define FINF __uint_as_float(0x7f800000u)

__device__ __forceinline__ bf16_t f2bf(float f) {
    uint32_t u = __float_as_uint(f);
    u = u + 0x7fffu + ((u >> 16) & 1u);   // round-to-nearest-even
    return (bf16_t)(u >> 16);
}
__device__ __forceinline__ float siluf(float x) {
    return x / (1.0f + __expf(-x));
}

// ---- prepack: W2 fp32 -> bf16 in MFMA B-fragment order ----
__global__ __launch_bounds__(256) void prepack_w2(
    const float* __restrict__ W2, uint4* __restrict__ w2b)
{
    int c  = blockIdx.x * 256 + threadIdx.x;
    int f  = c >> 6, ln = c & 63;
    int NT = f >> 2, kk = f & 3;
    int row = NT*16 + (ln & 15);
    int k0  = kk*32 + (ln >> 4) * 8;
    const float* s = W2 + row * HID + k0;
    float4 lo = *(const float4*)s;
    float4 hi = *(const float4*)(s + 4);
    uint4 pk;
    pk.x = (uint32_t)f2bf(lo.x) | ((uint32_t)f2bf(lo.y) << 16);
    pk.y = (uint32_t)f2bf(lo.z) | ((uint32_t)f2bf(lo.w) << 16);
    pk.z = (uint32_t)f2bf(hi.x) | ((uint32_t)f2bf(hi.y) << 16);
    pk.w = (uint32_t)f2bf(hi.z) | ((uint32_t)f2bf(hi.w) << 16);
    w2b[c] = pk;
}

template<bool WS>
struct __align__(16) Sm {
    union __align__(16) {                 // phase-disjoint reuse (24 KB)
        struct {
            ushort   dbf[NPB][NN];        // 16 KB: top-16 distance bits per j
            uint32_t hist[NPB][1024];     //  8 KB: sample-min histogram
        } sel;
        ushort h1[64 * HID];              // 16 KB: MLP A-operand, bf16, swizzled
    } u;
    uint32_t w2l[WS ? 4 : HID * 64];      // W2 LDS staging only in fallback
    uint32_t cand[NPB][CAP];              // 1 KB: (d16<<16)|j keys
    float ssqh[2][64];                    // per n-half partial sum-of-squares
    float sedgeh[2][64];                  // per n-half partial edge scalar
    int recvs[NPB][KK];
    int waveTot[NPB][8];
    unsigned long long redk[8];
    uint32_t excl[128];                   // fallback exclusion bitmap
    int pivotB[NPB];
    int cnt[NPB];
};

template<bool WS>
__global__ __launch_bounds__(BLK) void egnn_main(
    const float* __restrict__ pos, const float* __restrict__ tptr,
    const float* __restrict__ W1,  const float* __restrict__ b1,
    const float* __restrict__ g1,  const float* __restrict__ W2,
    const float* __restrict__ b2,  const float* __restrict__ g2,
    const float* __restrict__ W3,  const float* __restrict__ b3,
    const uint4* __restrict__ w2b, float* __restrict__ out)
{
    __shared__ Sm<WS> sm;
    const int tid  = threadIdx.x;
    const int lane = tid & 63;
    const int wid  = tid >> 6;            // 0..7
    const int bid  = blockIdx.x;
    const int i0   = NPB * bid, i1 = i0 + 1;
    const int l15  = lane & 15, lq = lane >> 4;

    const float ts  = tptr[0];
    const float b3s = b3[0];

    // closed-form RMS coefficients: sum_n (rad*a_n + c_n)^2 = rad^2*A2 + 2*rad*AC + C2
    // (each wave's 64 lanes cover all 128 layer-1 neurons; redundant per wave)
    float A2, AC, C2;
    {
        const float4 w1v = ((const float4*)W1)[lane];     // rows 2l,2l+1
        const float2 b1v = ((const float2*)b1)[lane];
        float t0 = ts * w1v.y + b1v.x;
        float t1 = ts * w1v.w + b1v.y;
        A2 = w1v.x*w1v.x + w1v.z*w1v.z;
        AC = w1v.x*t0    + w1v.z*t1;
        C2 = t0*t0       + t1*t1;
        #pragma unroll
        for (int m = 32; m >= 1; m >>= 1) {
            A2 += __shfl_xor(A2, m, 64);
            AC += __shfl_xor(AC, m, 64);
            C2 += __shfl_xor(C2, m, 64);
        }
    }

    if constexpr (!WS) {
        for (int idx = tid; idx < HID * 16; idx += BLK) {
            int row = idx >> 4, c = idx & 15;
            const float* src = W2 + row * HID + c * 8;
            float4 lo = *(const float4*)src;
            float4 hi = *(const float4*)(src + 4);
            uint4 pk;
            pk.x = (uint32_t)f2bf(lo.x) | ((uint32_t)f2bf(lo.y) << 16);
            pk.y = (uint32_t)f2bf(lo.z) | ((uint32_t)f2bf(lo.w) << 16);
            pk.z = (uint32_t)f2bf(hi.x) | ((uint32_t)f2bf(hi.y) << 16);
            pk.w = (uint32_t)f2bf(hi.z) | ((uint32_t)f2bf(hi.w) << 16);
            *((uint4*)&sm.w2l[row * 64 + 4 * (c ^ (row & 15))]) = pk;
        }
    }
    // zero sample histograms: 2048 dwords = 512 uint4, 1 per thread
    ((uint4*)sm.u.sel.hist)[tid] = uint4{0u, 0u, 0u, 0u};
    if (tid == 0) { sm.cnt[0] = 0; sm.cnt[1] = 0; }
    __syncthreads();                                            // B1

    // node centers: pos[6*bid .. +5] as 3x float2
    const float2 c01 = ((const float2*)pos)[3*bid    ];
    const float2 c23 = ((const float2*)pos)[3*bid + 1];
    const float2 c45 = ((const float2*)pos)[3*bid + 2];
    const float px0 = c01.x, py0 = c01.y, pz0 = c23.x;
    const float px1 = c23.y, py1 = c45.x, pz1 = c45.y;

    // ---- pass 1: sample mins + top-16 distance bits to LDS (8 j's per thread) ----
    float m0 = FINF, m1 = FINF;
    {
        const float4* p4 = (const float4*)pos;
        #pragma unroll
        for (int g = 0; g < 2; ++g) {
            float4 f0 = p4[1536*g + 3*tid];
            float4 f1 = p4[1536*g + 3*tid + 1];
            float4 f2 = p4[1536*g + 3*tid + 2];
            float jx[4] = {f0.x, f0.w, f1.z, f2.y};
            float jy[4] = {f0.y, f1.x, f1.w, f2.z};
            float jz[4] = {f0.z, f1.y, f2.x, f2.w};
            uint32_t lo0 = 0, hi0 = 0, lo1 = 0, hi1 = 0;
            #pragma unroll
            for (int c = 0; c < 4; ++c) {
                int j = 2048*g + 4*tid + c;
                float dx0 = px0 - jx[c], dy0 = py0 - jy[c], dz0 = pz0 - jz[c];
                float d0 = __fadd_rn(__fadd_rn(__fmul_rn(dx0,dx0), __fmul_rn(dy0,dy0)),
                                     __fmul_rn(dz0,dz0));
                if (j == i0) d0 = FINF;
                m0 = fminf(m0, d0);
                uint32_t t0 = __float_as_uint(d0) >> 16;
                float dx1 = px1 - jx[c], dy1 = py1 - jy[c], dz1 = pz1 - jz[c];
                float d1 = __fadd_rn(__fadd_rn(__fmul_rn(dx1,dx1), __fmul_rn(dy1,dy1)),
                                     __fmul_rn(dz1,dz1));
                if (j == i1) d1 = FINF;
                m1 = fminf(m1, d1);
                uint32_t t1 = __float_as_uint(d1) >> 16;
                if (c < 2) { lo0 |= t0 << (16*c);     lo1 |= t1 << (16*c); }
                else       { hi0 |= t0 << (16*(c-2)); hi1 |= t1 << (16*(c-2)); }
            }
            *((uint2*)&sm.u.sel.dbf[0][2048*g + 4*tid]) = make_uint2(lo0, hi0);
            *((uint2*)&sm.u.sel.dbf[1][2048*g + 4*tid]) = make_uint2(lo1, hi1);
        }
    }
    atomicAdd((int*)&sm.u.sel.hist[0][__float_as_uint(m0) >> 21], 1);
    atomicAdd((int*)&sm.u.sel.hist[1][__float_as_uint(m1) >> 21], 1);
    __syncthreads();                                            // B2

    // ---- pivot bucket B (sample-min bound; bucket = top-11 bits, exact) ----
    {
        const int b0 = tid * 2;
        uint2 qa = *(const uint2*)&sm.u.sel.hist[0][b0];
        uint2 qb = *(const uint2*)&sm.u.sel.hist[1][b0];
        int a0 = (int)qa.x, a1 = (int)qa.y;
        int e0 = (int)qb.x, e1 = (int)qb.y;
        int s0 = a0 + a1, s1 = e0 + e1;
        int in0 = s0, in1 = s1;
        #pragma unroll
        for (int off = 1; off < 64; off <<= 1) {
            int v0 = __shfl_up(in0, off, 64);
            int v1 = __shfl_up(in1, off, 64);
            if (lane >= off) { in0 += v0; in1 += v1; }
        }
        if (lane == 63) { sm.waveTot[0][wid] = in0; sm.waveTot[1][wid] = in1; }
        __syncthreads();                                        // B3
        int base0 = 0, base1 = 0;
        for (int w = 0; w < wid; ++w) { base0 += sm.waveTot[0][w]; base1 += sm.waveTot[1][w]; }
        int E0 = base0 + in0 - s0;
        if (E0 < KK && E0 + s0 >= KK)
            sm.pivotB[0] = (E0 + a0 >= KK) ? b0 : b0 + 1;
        int E1 = base1 + in1 - s1;
        if (E1 < KK && E1 + s1 >= KK)
            sm.pivotB[1] = (E1 + e0 >= KK) ? b0 : b0 + 1;
    }
    __syncthreads();                                            // B4

    // ---- pass 2: compaction from LDS d16; key = (d16<<16)|j ----
    {
        const int B0 = sm.pivotB[0], B1v = sm.pivotB[1];
        #pragma unroll
        for (int g = 0; g < 2; ++g) {
            uint2 v0 = *((const uint2*)&sm.u.sel.dbf[0][2048*g + 4*tid]);
            uint2 v1 = *((const uint2*)&sm.u.sel.dbf[1][2048*g + 4*tid]);
            uint32_t d16a[4] = {v0.x & 0xffffu, v0.x >> 16, v0.y & 0xffffu, v0.y >> 16};
            uint32_t d16b[4] = {v1.x & 0xffffu, v1.x >> 16, v1.y & 0xffffu, v1.y >> 16};
            #pragma unroll
            for (int c = 0; c < 4; ++c) {
                int j = 2048*g + 4*tid + c;
                if ((int)(d16a[c] >> 5) <= B0) {
                    int slot = atomicAdd(&sm.cnt[0], 1);
                    if (slot < CAP) sm.cand[0][slot] = (d16a[c] << 16) | (unsigned)j;
                }
                if ((int)(d16b[c] >> 5) <= B1v) {
                    int slot = atomicAdd(&sm.cnt[1], 1);
                    if (slot < CAP) sm.cand[1][slot] = (d16b[c] << 16) | (unsigned)j;
                }
            }
        }
    }
    __syncthreads();                                            // B5

    const int c0 = sm.cnt[0], c1v = sm.cnt[1];
    if (c0 <= CAP && c1v <= CAP) {
        // threads 0..255 rank node0 cands; 256..511 rank node1 (x4 unrolled reads)
        int nn = tid >> 8, tt = tid & 255;
        int cN = nn ? c1v : c0;
        if (tt < cN) {
            uint32_t km = sm.cand[nn][tt];
            int rank = 0;
            for (int q = 0; q < cN; q += 4) {
                uint4 v = *((const uint4*)&sm.cand[nn][q]);
                rank += (q     < cN && v.x < km) ? 1 : 0;
                rank += (q + 1 < cN && v.y < km) ? 1 : 0;
                rank += (q + 2 < cN && v.z < km) ? 1 : 0;
                rank += (q + 3 < cN && v.w < km) ? 1 : 0;
            }
            if (rank < KK) sm.recvs[nn][rank] = (int)(km & 0xFFFFu);
        }
    } else {
        // cold fallback (overflow; ~never): recompute argmin w/ exclusion bitmap
        for (int nn = 0; nn < NPB; ++nn) {
            if (tid < 128) sm.excl[tid] = 0u;
            __syncthreads();
            const int   iself = nn ? i1 : i0;
            const float pxn = nn ? px1 : px0;
            const float pyn = nn ? py1 : py0;
            const float pzn = nn ? pz1 : pz0;
            for (int it = 0; it < KK; ++it) {
                unsigned long long best = ~0ull;
                const float4* p4 = (const float4*)pos;
                for (int g = 0; g < 2; ++g) {
                    float4 f0 = p4[1536*g + 3*tid];
                    float4 f1 = p4[1536*g + 3*tid + 1];
                    float4 f2 = p4[1536*g + 3*tid + 2];
                    float jx[4] = {f0.x, f0.w, f1.z, f2.y};
                    float jy[4] = {f0.y, f1.x, f1.w, f2.z};
                    float jz[4] = {f0.z, f1.y, f2.x, f2.w};
                    for (int c = 0; c < 4; ++c) {
                        int j = 2048*g + 4*tid + c;
                        float dx = pxn - jx[c], dy = pyn - jy[c], dz = pzn - jz[c];
                        float d = __fadd_rn(__fadd_rn(__fmul_rn(dx,dx), __fmul_rn(dy,dy)),
                                            __fmul_rn(dz,dz));
                        bool dead = (j == iself) || ((sm.excl[j >> 5] >> (j & 31)) & 1u);
                        unsigned long long key = dead ? ~0ull
                            : ((((unsigned long long)__float_as_uint(d)) << 12) | (unsigned)j);
                        best = best < key ? best : key;
                    }
                }
                #pragma unroll
                for (int m = 32; m >= 1; m >>= 1) {
                    unsigned long long o = __shfl_xor(best, m, 64);
                    best = best < o ? best : o;
                }
                if (lane == 0) sm.redk[wid] = best;
                __syncthreads();
                if (tid == 0) {
                    unsigned long long b = sm.redk[0];
                    for (int w = 1; w < 8; ++w) b = b < sm.redk[w] ? b : sm.redk[w];
                    int j = (int)(b & 0xfffull);
                    sm.recvs[nn][it] = j;
                    atomicOr((unsigned int*)&sm.excl[j >> 5], 1u << (j & 31));
                }
                __syncthreads();
            }
        }
    }
    __syncthreads();                                            // B6

    // ---- layer 1 + edge gather: wave w owns h1 rows [8w, 8w+8) ----
    {
        const int ch = lane >> 2, epr = lane & 3;
        float4 wA = ((const float4*)W1)[ch*4    ];
        float4 wB = ((const float4*)W1)[ch*4 + 1];
        float4 wC = ((const float4*)W1)[ch*4 + 2];
        float4 wD = ((const float4*)W1)[ch*4 + 3];
        float4 bA = ((const float4*)b1)[ch*2], bB = ((const float4*)b1)[ch*2 + 1];
        float4 gA = ((const float4*)g1)[ch*2], gB = ((const float4*)g1)[ch*2 + 1];
        float av[8] = {wA.x, wA.z, wB.x, wB.z, wC.x, wC.z, wD.x, wD.z};
        float cv[8] = {ts*wA.y + bA.x, ts*wA.w + bA.y, ts*wB.y + bA.z, ts*wB.w + bA.w,
                       ts*wC.y + bB.x, ts*wC.w + bB.y, ts*wD.y + bB.z, ts*wD.w + bB.w};
        float gv[8] = {gA.x, gA.y, gA.z, gA.w, gB.x, gB.y, gB.z, gB.w};

        const int nodeW = wid >> 2;
        const float pxw = nodeW ? px1 : px0;
        const float pyw = nodeW ? py1 : py0;
        const float pzw = nodeW ? pz1 : pz0;
        uint4* h1q = (uint4*)sm.u.h1;
        #pragma unroll
        for (int g = 0; g < 2; ++g) {
            int E = 8*wid + 4*g + epr;
            int r = sm.recvs[nodeW][E & 31];
            float dx = pxw - pos[3*r];
            float dy = pyw - pos[3*r+1];
            float dz = pzw - pos[3*r+2];
            float rad = __fadd_rn(__fadd_rn(__fmul_rn(dx,dx), __fmul_rn(dy,dy)),
                                  __fmul_rn(dz,dz));
            float sqv = rad*rad*A2 + 2.0f*rad*AC + C2;
            float rn  = rsqrtf(sqv * (1.0f/HID) + 1e-5f);
            uint32_t pk[4];
            #pragma unroll
            for (int p = 0; p < 4; ++p) {
                float va = siluf((rad*av[2*p]   + cv[2*p])   * rn * gv[2*p]);
                float vb = siluf((rad*av[2*p+1] + cv[2*p+1]) * rn * gv[2*p+1]);
                pk[p] = (__float_as_uint(va) >> 16) | (__float_as_uint(vb) & 0xffff0000u);
            }
            h1q[E*16 + (ch ^ (E & 15))] = uint4{pk[0], pk[1], pk[2], pk[3]};
        }
    }
    __syncthreads();                                            // B7 (m-tiles span wave pairs)

    // ---- layer 2 via MFMA: wave pair (t = wid>>1, nh = wid&1) ----
    // wave computes m-tile t (16 edges) x 4 n-tiles (n-half nh): acc[4] = 16 VGPRs
    const int tmt = wid >> 1, nh = wid & 1;
    f32x4 acc[4];
    #pragma unroll
    for (int nt = 0; nt < 4; ++nt) acc[nt] = f32x4{0.f, 0.f, 0.f, 0.f};
    {
        const bf16x8* h1v = (const bf16x8*)sm.u.h1;   // [64][16 chunks]
        const int m = 16*tmt + l15;
        if constexpr (WS) {
            const bf16x8* bv = (const bf16x8*)w2b;
            #pragma unroll
            for (int kk = 0; kk < 4; ++kk) {
                bf16x8 af = h1v[m*16 + ((kk*4 + lq) ^ l15)];
                #pragma unroll
                for (int nt = 0; nt < 4; ++nt)
                    acc[nt] = __builtin_amdgcn_mfma_f32_16x16x32_bf16(
                                  af, bv[((nh*4 + nt)*4 + kk)*64 + lane], acc[nt], 0, 0, 0);
            }
        } else {
            const bf16x8* w2v = (const bf16x8*)sm.w2l;    // [128][16 chunks]
            #pragma unroll
            for (int kk = 0; kk < 4; ++kk) {
                const int q = (kk*4 + lq) ^ l15;
                bf16x8 af = h1v[m*16 + q];
                #pragma unroll
                for (int nt = 0; nt < 4; ++nt)
                    acc[nt] = __builtin_amdgcn_mfma_f32_16x16x32_bf16(
                                  af, w2v[((nh*4 + nt)*16 + l15)*16 + q], acc[nt], 0, 0, 0);
            }
        }
    }

    // ---- epilogue: RMS over 128 = this wave's 64 neurons + paired wave's 64 ----
    float g2v[4], w3v[4], b2v[4];
    #pragma unroll
    for (int nt = 0; nt < 4; ++nt) {
        int n = (nh*4 + nt)*16 + l15;
        g2v[nt] = g2[n]; w3v[nt] = W3[n]; b2v[nt] = b2[n];
    }
    float ss[4];
    #pragma unroll
    for (int r = 0; r < 4; ++r) {
        float t = 0.f;
        #pragma unroll
        for (int nt = 0; nt < 4; ++nt) {
            float zz = acc[nt][r] + b2v[nt];
            acc[nt][r] = zz;
            t += zz*zz;
        }
        ss[r] = t;
    }
    #pragma unroll
    for (int m = 8; m >= 1; m >>= 1) {
        #pragma unroll
        for (int r = 0; r < 4; ++r) ss[r] += __shfl_xor(ss[r], m, 64);
    }
    if (l15 == 0) {
        #pragma unroll
        for (int r = 0; r < 4; ++r) sm.ssqh[nh][16*tmt + lq*4 + r] = ss[r];
    }
    __syncthreads();                                            // B8

    float sp[4];
    #pragma unroll
    for (int r = 0; r < 4; ++r) {
        int e = 16*tmt + lq*4 + r;
        float rn = rsqrtf((sm.ssqh[0][e] + sm.ssqh[1][e]) * (1.0f/HID) + 1e-5f);
        float t = 0.f;
        #pragma unroll
        for (int nt = 0; nt < 4; ++nt)
            t += siluf(acc[nt][r] * rn * g2v[nt]) * w3v[nt];
        sp[r] = t;
    }
    #pragma unroll
    for (int m = 8; m >= 1; m >>= 1) {
        #pragma unroll
        for (int r = 0; r < 4; ++r) sp[r] += __shfl_xor(sp[r], m, 64);
    }
    if (l15 == 0) {
        #pragma unroll
        for (int r = 0; r < 4; ++r) sm.sedgeh[nh][16*tmt + lq*4 + r] = sp[r];
    }
    __syncthreads();                                            // B9

    // ---- final: wave w (w<2) sums node w's 32 edge messages lane-parallel ----
    if (wid < NPB) {
        float mx = 0.f, my = 0.f, mz = 0.f;
        if (lane < KK) {
            int e = KK*wid + lane;
            int r = sm.recvs[wid][lane];
            float cx = (wid ? px1 : px0) - pos[3*r];
            float cy = (wid ? py1 : py0) - pos[3*r+1];
            float cz = (wid ? pz1 : pz0) - pos[3*r+2];
            float s  = sm.sedgeh[0][e] + sm.sedgeh[1][e] + b3s;
            mx = cx * s; my = cy * s; mz = cz * s;
        }
        #pragma unroll
        for (int m = 16; m >= 1; m >>= 1) {
            mx += __shfl_xor(mx, m, 64);
            my += __shfl_xor(my, m, 64);
            mz += __shfl_xor(mz, m, 64);
        }
        if (lane == 0) {
            int node = i0 + wid;
            out[3*node    ] = (wid ? px1 : px0) + mx * (1.0f/KK);
            out[3*node + 1] = (wid ? py1 : py0) + my * (1.0f/KK);
            out[3*node + 2] = (wid ? pz1 : pz0) + mz * (1.0f/KK);
        }
    }
}

extern "C" void kernel_launch(void* const* d_in, const int* in_sizes, int n_in,
                              void* d_out, int out_size, void* d_ws, size_t ws_size,
                              hipStream_t stream) {
    (void)in_sizes; (void)n_in; (void)out_size;
    const float* pos = (const float*)d_in[0];
    const float* t   = (const float*)d_in[1];
    const float* W1  = (const float*)d_in[2];
    const float* b1  = (const float*)d_in[3];
    const float* g1  = (const float*)d_in[4];
    const float* W2  = (const float*)d_in[5];
    const float* b2  = (const float*)d_in[6];
    const float* g2  = (const float*)d_in[7];
    const float* W3  = (const float*)d_in[8];
    const float* b3  = (const float*)d_in[9];
    float* out = (float*)d_out;

    if (d_ws != nullptr && ws_size >= 32768) {
        prepack_w2<<<8, 256, 0, stream>>>(W2, (uint4*)d_ws);
        egnn_main<true><<<GRID, BLK, 0, stream>>>(
            pos, t, W1, b1, g1, W2, b2, g2, W3, b3, (const uint4*)d_ws, out);
    } else {
        egnn_main<false><<<GRID, BLK, 0, stream>>>(
            pos, t, W1, b1, g1, W2, b2, g2, W3, b3, nullptr, out);
    }
}

// Round 16
// 122.733 us; speedup vs baseline: 1.0990x; 1.0097x over previous
//
#include <hip/hip_runtime.h>
#include <stdint.h>

#define NN   4096
#define KK   32
#define HID  128
#define BLK  512
#define NPB  2
#define GRID (NN / NPB)
#define CAP  128

typedef unsigned short bf16_t;
typedef __attribute__((ext_vector_type(8))) short bf16x8;
typedef __attribute__((ext_vector_type(4))) float f32x4;

#define FINF __uint_as_float(0x7f800000u)

__device__ __forceinline__ bf16_t f2bf(float f) {
    uint32_t u = __float_as_uint(f);
    u = u + 0x7fffu + ((u >> 16) & 1u);   // round-to-nearest-even
    return (bf16_t)(u >> 16);
}
__device__ __forceinline__ float siluf(float x) {
    return x / (1.0f + __expf(-x));
}

// ---- prepack: W2 fp32 -> bf16 in MFMA B-fragment order ----
__global__ __launch_bounds__(256) void prepack_w2(
    const float* __restrict__ W2, uint4* __restrict__ w2b)
{
    int c  = blockIdx.x * 256 + threadIdx.x;
    int f  = c >> 6, ln = c & 63;
    int NT = f >> 2, kk = f & 3;
    int row = NT*16 + (ln & 15);
    int k0  = kk*32 + (ln >> 4) * 8;
    const float* s = W2 + row * HID + k0;
    float4 lo = *(const float4*)s;
    float4 hi = *(const float4*)(s + 4);
    uint4 pk;
    pk.x = (uint32_t)f2bf(lo.x) | ((uint32_t)f2bf(lo.y) << 16);
    pk.y = (uint32_t)f2bf(lo.z) | ((uint32_t)f2bf(lo.w) << 16);
    pk.z = (uint32_t)f2bf(hi.x) | ((uint32_t)f2bf(hi.y) << 16);
    pk.w = (uint32_t)f2bf(hi.z) | ((uint32_t)f2bf(hi.w) << 16);
    w2b[c] = pk;
}

template<bool WS>
struct __align__(16) Sm {
    union __align__(16) {                 // phase-disjoint reuse (16 KB)
        uint32_t hist[NPB][1024];         // 8 KB: sample-min histogram
        ushort h1[64 * HID];              // 16 KB: MLP A-operand, bf16, swizzled
    } u;
    uint32_t w2l[WS ? 4 : HID * 64];      // W2 LDS staging only in fallback
    uint32_t cand[NPB][CAP];              // 1 KB: (d16<<16)|j keys
    float ssqh[2][64];                    // per n-half partial sum-of-squares
    float sedgeh[2][64];                  // per n-half partial edge scalar
    int recvs[NPB][KK];
    int waveTot[NPB][8];
    unsigned long long redk[8];
    uint32_t excl[128];                   // fallback exclusion bitmap
    int pivotB[NPB];
    int cnt[NPB];
};

template<bool WS>
__global__ __launch_bounds__(BLK) void egnn_main(
    const float* __restrict__ pos, const float* __restrict__ tptr,
    const float* __restrict__ W1,  const float* __restrict__ b1,
    const float* __restrict__ g1,  const float* __restrict__ W2,
    const float* __restrict__ b2,  const float* __restrict__ g2,
    const float* __restrict__ W3,  const float* __restrict__ b3,
    const uint4* __restrict__ w2b, float* __restrict__ out)
{
    __shared__ Sm<WS> sm;
    const int tid  = threadIdx.x;
    const int lane = tid & 63;
    const int wid  = tid >> 6;            // 0..7
    const int bid  = blockIdx.x;
    const int i0   = NPB * bid, i1 = i0 + 1;
    const int l15  = lane & 15, lq = lane >> 4;

    const float ts  = tptr[0];
    const float b3s = b3[0];

    // closed-form RMS coefficients: sum_n (rad*a_n + c_n)^2 = rad^2*A2 + 2*rad*AC + C2
    float A2, AC, C2;
    {
        const float4 w1v = ((const float4*)W1)[lane];     // rows 2l,2l+1
        const float2 b1v = ((const float2*)b1)[lane];
        float t0 = ts * w1v.y + b1v.x;
        float t1 = ts * w1v.w + b1v.y;
        A2 = w1v.x*w1v.x + w1v.z*w1v.z;
        AC = w1v.x*t0    + w1v.z*t1;
        C2 = t0*t0       + t1*t1;
        #pragma unroll
        for (int m = 32; m >= 1; m >>= 1) {
            A2 += __shfl_xor(A2, m, 64);
            AC += __shfl_xor(AC, m, 64);
            C2 += __shfl_xor(C2, m, 64);
        }
    }

    if constexpr (!WS) {
        for (int idx = tid; idx < HID * 16; idx += BLK) {
            int row = idx >> 4, c = idx & 15;
            const float* src = W2 + row * HID + c * 8;
            float4 lo = *(const float4*)src;
            float4 hi = *(const float4*)(src + 4);
            uint4 pk;
            pk.x = (uint32_t)f2bf(lo.x) | ((uint32_t)f2bf(lo.y) << 16);
            pk.y = (uint32_t)f2bf(lo.z) | ((uint32_t)f2bf(lo.w) << 16);
            pk.z = (uint32_t)f2bf(hi.x) | ((uint32_t)f2bf(hi.y) << 16);
            pk.w = (uint32_t)f2bf(hi.z) | ((uint32_t)f2bf(hi.w) << 16);
            *((uint4*)&sm.w2l[row * 64 + 4 * (c ^ (row & 15))]) = pk;
        }
    }
    // zero sample histograms: 2048 dwords = 512 uint4, 1 per thread
    ((uint4*)sm.u.hist)[tid] = uint4{0u, 0u, 0u, 0u};
    if (tid == 0) { sm.cnt[0] = 0; sm.cnt[1] = 0; }
    __syncthreads();                                            // B1

    // node centers: pos[6*bid .. +5] as 3x float2
    const float2 c01 = ((const float2*)pos)[3*bid    ];
    const float2 c23 = ((const float2*)pos)[3*bid + 1];
    const float2 c45 = ((const float2*)pos)[3*bid + 2];
    const float px0 = c01.x, py0 = c01.y, pz0 = c23.x;
    const float px1 = c23.y, py1 = c45.x, pz1 = c45.y;

    // ---- pass 1: sample mins; packed top-16 distance bits kept in REGISTERS ----
    float m0 = FINF, m1 = FINF;
    uint32_t da[4], db[4];                // d16 pairs: da[2g],da[2g+1] = lo,hi of group g
    {
        const float4* p4 = (const float4*)pos;
        #pragma unroll
        for (int g = 0; g < 2; ++g) {
            float4 f0 = p4[1536*g + 3*tid];
            float4 f1 = p4[1536*g + 3*tid + 1];
            float4 f2 = p4[1536*g + 3*tid + 2];
            float jx[4] = {f0.x, f0.w, f1.z, f2.y};
            float jy[4] = {f0.y, f1.x, f1.w, f2.z};
            float jz[4] = {f0.z, f1.y, f2.x, f2.w};
            uint32_t lo0 = 0, hi0 = 0, lo1 = 0, hi1 = 0;
            #pragma unroll
            for (int c = 0; c < 4; ++c) {
                int j = 2048*g + 4*tid + c;
                float dx0 = px0 - jx[c], dy0 = py0 - jy[c], dz0 = pz0 - jz[c];
                float d0 = __fadd_rn(__fadd_rn(__fmul_rn(dx0,dx0), __fmul_rn(dy0,dy0)),
                                     __fmul_rn(dz0,dz0));
                if (j == i0) d0 = FINF;
                m0 = fminf(m0, d0);
                uint32_t t0 = __float_as_uint(d0) >> 16;
                float dx1 = px1 - jx[c], dy1 = py1 - jy[c], dz1 = pz1 - jz[c];
                float d1 = __fadd_rn(__fadd_rn(__fmul_rn(dx1,dx1), __fmul_rn(dy1,dy1)),
                                     __fmul_rn(dz1,dz1));
                if (j == i1) d1 = FINF;
                m1 = fminf(m1, d1);
                uint32_t t1 = __float_as_uint(d1) >> 16;
                if (c < 2) { lo0 |= t0 << (16*c);     lo1 |= t1 << (16*c); }
                else       { hi0 |= t0 << (16*(c-2)); hi1 |= t1 << (16*(c-2)); }
            }
            da[2*g] = lo0; da[2*g+1] = hi0;
            db[2*g] = lo1; db[2*g+1] = hi1;
        }
    }
    atomicAdd((int*)&sm.u.hist[0][__float_as_uint(m0) >> 21], 1);
    atomicAdd((int*)&sm.u.hist[1][__float_as_uint(m1) >> 21], 1);
    __syncthreads();                                            // B2

    // ---- pivot bucket B (sample-min bound; bucket = top-11 bits, exact) ----
    {
        const int b0 = tid * 2;
        uint2 qa = *(const uint2*)&sm.u.hist[0][b0];
        uint2 qb = *(const uint2*)&sm.u.hist[1][b0];
        int a0 = (int)qa.x, a1 = (int)qa.y;
        int e0 = (int)qb.x, e1 = (int)qb.y;
        int s0 = a0 + a1, s1 = e0 + e1;
        int in0 = s0, in1 = s1;
        #pragma unroll
        for (int off = 1; off < 64; off <<= 1) {
            int v0 = __shfl_up(in0, off, 64);
            int v1 = __shfl_up(in1, off, 64);
            if (lane >= off) { in0 += v0; in1 += v1; }
        }
        if (lane == 63) { sm.waveTot[0][wid] = in0; sm.waveTot[1][wid] = in1; }
        __syncthreads();                                        // B3
        int base0 = 0, base1 = 0;
        for (int w = 0; w < wid; ++w) { base0 += sm.waveTot[0][w]; base1 += sm.waveTot[1][w]; }
        int E0 = base0 + in0 - s0;
        if (E0 < KK && E0 + s0 >= KK)
            sm.pivotB[0] = (E0 + a0 >= KK) ? b0 : b0 + 1;
        int E1 = base1 + in1 - s1;
        if (E1 < KK && E1 + s1 >= KK)
            sm.pivotB[1] = (E1 + e0 >= KK) ? b0 : b0 + 1;
    }
    __syncthreads();                                            // B4

    // ---- pass 2: compaction from REGISTER d16; key = (d16<<16)|j ----
    {
        const int B0 = sm.pivotB[0], B1v = sm.pivotB[1];
        #pragma unroll
        for (int g = 0; g < 2; ++g) {
            uint32_t d16a[4] = {da[2*g] & 0xffffu, da[2*g] >> 16,
                                da[2*g+1] & 0xffffu, da[2*g+1] >> 16};
            uint32_t d16b[4] = {db[2*g] & 0xffffu, db[2*g] >> 16,
                                db[2*g+1] & 0xffffu, db[2*g+1] >> 16};
            #pragma unroll
            for (int c = 0; c < 4; ++c) {
                int j = 2048*g + 4*tid + c;
                if ((int)(d16a[c] >> 5) <= B0) {
                    int slot = atomicAdd(&sm.cnt[0], 1);
                    if (slot < CAP) sm.cand[0][slot] = (d16a[c] << 16) | (unsigned)j;
                }
                if ((int)(d16b[c] >> 5) <= B1v) {
                    int slot = atomicAdd(&sm.cnt[1], 1);
                    if (slot < CAP) sm.cand[1][slot] = (d16b[c] << 16) | (unsigned)j;
                }
            }
        }
    }
    __syncthreads();                                            // B5

    const int c0 = sm.cnt[0], c1v = sm.cnt[1];
    if (c0 <= CAP && c1v <= CAP) {
        // threads 0..255 rank node0 cands; 256..511 rank node1 (x4 unrolled reads)
        int nn = tid >> 8, tt = tid & 255;
        int cN = nn ? c1v : c0;
        if (tt < cN) {
            uint32_t km = sm.cand[nn][tt];
            int rank = 0;
            for (int q = 0; q < cN; q += 4) {
                uint4 v = *((const uint4*)&sm.cand[nn][q]);
                rank += (q     < cN && v.x < km) ? 1 : 0;
                rank += (q + 1 < cN && v.y < km) ? 1 : 0;
                rank += (q + 2 < cN && v.z < km) ? 1 : 0;
                rank += (q + 3 < cN && v.w < km) ? 1 : 0;
            }
            if (rank < KK) sm.recvs[nn][rank] = (int)(km & 0xFFFFu);
        }
    } else {
        // cold fallback (overflow; ~never): recompute argmin w/ exclusion bitmap
        for (int nn = 0; nn < NPB; ++nn) {
            if (tid < 128) sm.excl[tid] = 0u;
            __syncthreads();
            const int   iself = nn ? i1 : i0;
            const float pxn = nn ? px1 : px0;
            const float pyn = nn ? py1 : py0;
            const float pzn = nn ? pz1 : pz0;
            for (int it = 0; it < KK; ++it) {
                unsigned long long best = ~0ull;
                const float4* p4 = (const float4*)pos;
                for (int g = 0; g < 2; ++g) {
                    float4 f0 = p4[1536*g + 3*tid];
                    float4 f1 = p4[1536*g + 3*tid + 1];
                    float4 f2 = p4[1536*g + 3*tid + 2];
                    float jx[4] = {f0.x, f0.w, f1.z, f2.y};
                    float jy[4] = {f0.y, f1.x, f1.w, f2.z};
                    float jz[4] = {f0.z, f1.y, f2.x, f2.w};
                    for (int c = 0; c < 4; ++c) {
                        int j = 2048*g + 4*tid + c;
                        float dx = pxn - jx[c], dy = pyn - jy[c], dz = pzn - jz[c];
                        float d = __fadd_rn(__fadd_rn(__fmul_rn(dx,dx), __fmul_rn(dy,dy)),
                                            __fmul_rn(dz,dz));
                        bool dead = (j == iself) || ((sm.excl[j >> 5] >> (j & 31)) & 1u);
                        unsigned long long key = dead ? ~0ull
                            : ((((unsigned long long)__float_as_uint(d)) << 12) | (unsigned)j);
                        best = best < key ? best : key;
                    }
                }
                #pragma unroll
                for (int m = 32; m >= 1; m >>= 1) {
                    unsigned long long o = __shfl_xor(best, m, 64);
                    best = best < o ? best : o;
                }
                if (lane == 0) sm.redk[wid] = best;
                __syncthreads();
                if (tid == 0) {
                    unsigned long long b = sm.redk[0];
                    for (int w = 1; w < 8; ++w) b = b < sm.redk[w] ? b : sm.redk[w];
                    int j = (int)(b & 0xfffull);
                    sm.recvs[nn][it] = j;
                    atomicOr((unsigned int*)&sm.excl[j >> 5], 1u << (j & 31));
                }
                __syncthreads();
            }
        }
    }
    __syncthreads();                                            // B6

    // ---- layer 1 + edge gather: wave w owns h1 rows [8w, 8w+8) ----
    {
        const int ch = lane >> 2, epr = lane & 3;
        float4 wA = ((const float4*)W1)[ch*4    ];
        float4 wB = ((const float4*)W1)[ch*4 + 1];
        float4 wC = ((const float4*)W1)[ch*4 + 2];
        float4 wD = ((const float4*)W1)[ch*4 + 3];
        float4 bA = ((const float4*)b1)[ch*2], bB = ((const float4*)b1)[ch*2 + 1];
        float4 gA = ((const float4*)g1)[ch*2], gB = ((const float4*)g1)[ch*2 + 1];
        float av[8] = {wA.x, wA.z, wB.x, wB.z, wC.x, wC.z, wD.x, wD.z};
        float cv[8] = {ts*wA.y + bA.x, ts*wA.w + bA.y, ts*wB.y + bA.z, ts*wB.w + bA.w,
                       ts*wC.y + bB.x, ts*wC.w + bB.y, ts*wD.y + bB.z, ts*wD.w + bB.w};
        float gv[8] = {gA.x, gA.y, gA.z, gA.w, gB.x, gB.y, gB.z, gB.w};

        const int nodeW = wid >> 2;
        const float pxw = nodeW ? px1 : px0;
        const float pyw = nodeW ? py1 : py0;
        const float pzw = nodeW ? pz1 : pz0;
        uint4* h1q = (uint4*)sm.u.h1;
        #pragma unroll
        for (int g = 0; g < 2; ++g) {
            int E = 8*wid + 4*g + epr;
            int r = sm.recvs[nodeW][E & 31];
            float dx = pxw - pos[3*r];
            float dy = pyw - pos[3*r+1];
            float dz = pzw - pos[3*r+2];
            float rad = __fadd_rn(__fadd_rn(__fmul_rn(dx,dx), __fmul_rn(dy,dy)),
                                  __fmul_rn(dz,dz));
            float sqv = rad*rad*A2 + 2.0f*rad*AC + C2;
            float rn  = rsqrtf(sqv * (1.0f/HID) + 1e-5f);
            uint32_t pk[4];
            #pragma unroll
            for (int p = 0; p < 4; ++p) {
                float va = siluf((rad*av[2*p]   + cv[2*p])   * rn * gv[2*p]);
                float vb = siluf((rad*av[2*p+1] + cv[2*p+1]) * rn * gv[2*p+1]);
                pk[p] = (__float_as_uint(va) >> 16) | (__float_as_uint(vb) & 0xffff0000u);
            }
            h1q[E*16 + (ch ^ (E & 15))] = uint4{pk[0], pk[1], pk[2], pk[3]};
        }
    }
    __syncthreads();                                            // B7 (m-tiles span wave pairs)

    // ---- layer 2 via MFMA: wave pair (t = wid>>1, nh = wid&1) ----
    const int tmt = wid >> 1, nh = wid & 1;
    f32x4 acc[4];
    #pragma unroll
    for (int nt = 0; nt < 4; ++nt) acc[nt] = f32x4{0.f, 0.f, 0.f, 0.f};
    {
        const bf16x8* h1v = (const bf16x8*)sm.u.h1;   // [64][16 chunks]
        const int m = 16*tmt + l15;
        if constexpr (WS) {
            const bf16x8* bv = (const bf16x8*)w2b;
            #pragma unroll
            for (int kk = 0; kk < 4; ++kk) {
                bf16x8 af = h1v[m*16 + ((kk*4 + lq) ^ l15)];
                #pragma unroll
                for (int nt = 0; nt < 4; ++nt)
                    acc[nt] = __builtin_amdgcn_mfma_f32_16x16x32_bf16(
                                  af, bv[((nh*4 + nt)*4 + kk)*64 + lane], acc[nt], 0, 0, 0);
            }
        } else {
            const bf16x8* w2v = (const bf16x8*)sm.w2l;    // [128][16 chunks]
            #pragma unroll
            for (int kk = 0; kk < 4; ++kk) {
                const int q = (kk*4 + lq) ^ l15;
                bf16x8 af = h1v[m*16 + q];
                #pragma unroll
                for (int nt = 0; nt < 4; ++nt)
                    acc[nt] = __builtin_amdgcn_mfma_f32_16x16x32_bf16(
                                  af, w2v[((nh*4 + nt)*16 + l15)*16 + q], acc[nt], 0, 0, 0);
            }
        }
    }

    // ---- epilogue: RMS over 128 = this wave's 64 neurons + paired wave's 64 ----
    float g2v[4], w3v[4], b2v[4];
    #pragma unroll
    for (int nt = 0; nt < 4; ++nt) {
        int n = (nh*4 + nt)*16 + l15;
        g2v[nt] = g2[n]; w3v[nt] = W3[n]; b2v[nt] = b2[n];
    }
    float ss[4];
    #pragma unroll
    for (int r = 0; r < 4; ++r) {
        float t = 0.f;
        #pragma unroll
        for (int nt = 0; nt < 4; ++nt) {
            float zz = acc[nt][r] + b2v[nt];
            acc[nt][r] = zz;
            t += zz*zz;
        }
        ss[r] = t;
    }
    #pragma unroll
    for (int m = 8; m >= 1; m >>= 1) {
        #pragma unroll
        for (int r = 0; r < 4; ++r) ss[r] += __shfl_xor(ss[r], m, 64);
    }
    if (l15 == 0) {
        #pragma unroll
        for (int r = 0; r < 4; ++r) sm.ssqh[nh][16*tmt + lq*4 + r] = ss[r];
    }
    __syncthreads();                                            // B8

    float sp[4];
    #pragma unroll
    for (int r = 0; r < 4; ++r) {
        int e = 16*tmt + lq*4 + r;
        float rn = rsqrtf((sm.ssqh[0][e] + sm.ssqh[1][e]) * (1.0f/HID) + 1e-5f);
        float t = 0.f;
        #pragma unroll
        for (int nt = 0; nt < 4; ++nt)
            t += siluf(acc[nt][r] * rn * g2v[nt]) * w3v[nt];
        sp[r] = t;
    }
    #pragma unroll
    for (int m = 8; m >= 1; m >>= 1) {
        #pragma unroll
        for (int r = 0; r < 4; ++r) sp[r] += __shfl_xor(sp[r], m, 64);
    }
    if (l15 == 0) {
        #pragma unroll
        for (int r = 0; r < 4; ++r) sm.sedgeh[nh][16*tmt + lq*4 + r] = sp[r];
    }
    __syncthreads();                                            // B9

    // ---- final: wave w (w<2) sums node w's 32 edge messages lane-parallel ----
    if (wid < NPB) {
        float mx = 0.f, my = 0.f, mz = 0.f;
        if (lane < KK) {
            int e = KK*wid + lane;
            int r = sm.recvs[wid][lane];
            float cx = (wid ? px1 : px0) - pos[3*r];
            float cy = (wid ? py1 : py0) - pos[3*r+1];
            float cz = (wid ? pz1 : pz0) - pos[3*r+2];
            float s  = sm.sedgeh[0][e] + sm.sedgeh[1][e] + b3s;
            mx = cx * s; my = cy * s; mz = cz * s;
        }
        #pragma unroll
        for (int m = 16; m >= 1; m >>= 1) {
            mx += __shfl_xor(mx, m, 64);
            my += __shfl_xor(my, m, 64);
            mz += __shfl_xor(mz, m, 64);
        }
        if (lane == 0) {
            int node = i0 + wid;
            out[3*node    ] = (wid ? px1 : px0) + mx * (1.0f/KK);
            out[3*node + 1] = (wid ? py1 : py0) + my * (1.0f/KK);
            out[3*node + 2] = (wid ? pz1 : pz0) + mz * (1.0f/KK);
        }
    }
}

extern "C" void kernel_launch(void* const* d_in, const int* in_sizes, int n_in,
                              void* d_out, int out_size, void* d_ws, size_t ws_size,
                              hipStream_t stream) {
    (void)in_sizes; (void)n_in; (void)out_size;
    const float* pos = (const float*)d_in[0];
    const float* t   = (const float*)d_in[1];
    const float* W1  = (const float*)d_in[2];
    const float* b1  = (const float*)d_in[3];
    const float* g1  = (const float*)d_in[4];
    const float* W2  = (const float*)d_in[5];
    const float* b2  = (const float*)d_in[6];
    const float* g2  = (const float*)d_in[7];
    const float* W3  = (const float*)d_in[8];
    const float* b3  = (const float*)d_in[9];
    float* out = (float*)d_out;

    if (d_ws != nullptr && ws_size >= 32768) {
        prepack_w2<<<8, 256, 0, stream>>>(W2, (uint4*)d_ws);
        egnn_main<true><<<GRID, BLK, 0, stream>>>(
            pos, t, W1, b1, g1, W2, b2, g2, W3, b3, (const uint4*)d_ws, out);
    } else {
        egnn_main<false><<<GRID, BLK, 0, stream>>>(
            pos, t, W1, b1, g1, W2, b2, g2, W3, b3, nullptr, out);
    }
}

// Round 17
// 120.876 us; speedup vs baseline: 1.1158x; 1.0154x over previous
//
#include <hip/hip_runtime.h>
#include <stdint.h>

#define NN   4096
#define KK   32
#define HID  128
#define BLK  256
#define WPB  4                 // waves per block = nodes per block
#define GRID (NN / WPB)
#define CAP  128

typedef unsigned short bf16_t;
typedef __attribute__((ext_vector_type(8))) short bf16x8;
typedef __attribute__((ext_vector_type(4))) float f32x4;

#define FINF __uint_as_float(0x7f800000u)

__device__ __forceinline__ bf16_t f2bf(float f) {
    uint32_t u = __float_as_uint(f);
    u = u + 0x7fffu + ((u >> 16) & 1u);   // round-to-nearest-even
    return (bf16_t)(u >> 16);
}
__device__ __forceinline__ float siluf(float x) {
    return x / (1.0f + __expf(-x));
}

// 4 distances for j = g*256 + 4*lane + c (exact fp32 chain; self -> inf)
__device__ __forceinline__ void dist4(const float4* __restrict__ p4, int g, int lane,
                                      float px, float py, float pz, int iself,
                                      float d[4]) {
    float4 f0 = p4[g*192 + 3*lane];
    float4 f1 = p4[g*192 + 3*lane + 1];
    float4 f2 = p4[g*192 + 3*lane + 2];
    float jx[4] = {f0.x, f0.w, f1.z, f2.y};
    float jy[4] = {f0.y, f1.x, f1.w, f2.z};
    float jz[4] = {f0.z, f1.y, f2.x, f2.w};
    #pragma unroll
    for (int c = 0; c < 4; ++c) {
        int j = g*256 + 4*lane + c;
        float dx = px - jx[c], dy = py - jy[c], dz = pz - jz[c];
        float dd = __fadd_rn(__fadd_rn(__fmul_rn(dx,dx), __fmul_rn(dy,dy)),
                             __fmul_rn(dz,dz));
        d[c] = (j == iself) ? FINF : dd;
    }
}

// ---- prepack: W2 fp32 -> bf16 in MFMA B-fragment order (frag f = NT*4+kk) ----
__global__ __launch_bounds__(256) void prepack_w2(
    const float* __restrict__ W2, uint4* __restrict__ w2b)
{
    int c  = blockIdx.x * 256 + threadIdx.x;
    int f  = c >> 6, ln = c & 63;
    int NT = f >> 2, kk = f & 3;
    int row = NT*16 + (ln & 15);
    int k0  = kk*32 + (ln >> 4) * 8;
    const float* s = W2 + row * HID + k0;
    float4 lo = *(const float4*)s;
    float4 hi = *(const float4*)(s + 4);
    uint4 pk;
    pk.x = (uint32_t)f2bf(lo.x) | ((uint32_t)f2bf(lo.y) << 16);
    pk.y = (uint32_t)f2bf(lo.z) | ((uint32_t)f2bf(lo.w) << 16);
    pk.z = (uint32_t)f2bf(hi.x) | ((uint32_t)f2bf(hi.y) << 16);
    pk.w = (uint32_t)f2bf(hi.z) | ((uint32_t)f2bf(hi.w) << 16);
    w2b[c] = pk;
}

template<bool WS>
struct __align__(16) Sm {
    ushort   h1[WPB][KK * HID];     // 32 KB: per-wave A-operand (32 edges x 128)
    uint32_t cand[WPB][CAP];        // 2 KB : per-wave (d16<<16)|j keys
    float    rads[WPB][KK];         // per-wave edge radial
    float    sedge[WPB][KK];        // per-wave edge scalar
    int      recvs[WPB][KK];        // per-wave neighbor ids
    int      cnt[WPB];
    uint32_t w2l[WS ? 4 : HID * 64];// W2 LDS staging only in no-workspace fallback
};

template<bool WS>
__global__ __launch_bounds__(BLK) void egnn_main(
    const float* __restrict__ pos, const float* __restrict__ tptr,
    const float* __restrict__ W1,  const float* __restrict__ b1,
    const float* __restrict__ g1,  const float* __restrict__ W2,
    const float* __restrict__ b2,  const float* __restrict__ g2,
    const float* __restrict__ W3,  const float* __restrict__ b3,
    const uint4* __restrict__ w2b, float* __restrict__ out)
{
    __shared__ Sm<WS> sm;
    const int tid  = threadIdx.x;
    const int lane = tid & 63;
    const int wid  = tid >> 6;                  // 0..3: this wave / its node
    const int i    = blockIdx.x * WPB + wid;    // node handled by this wave
    const int l15  = lane & 15, lq = lane >> 4;

    const float ts  = tptr[0];
    const float b3s = b3[0];

    // closed-form RMS coefficients (wave-reduced -> lane-uniform):
    // sum_n (rad*a_n + c_n)^2 = rad^2*A2 + 2*rad*AC + C2
    float A2, AC, C2;
    {
        const float4 w1v = ((const float4*)W1)[lane];     // rows 2l,2l+1
        const float2 b1v = ((const float2*)b1)[lane];
        float t0 = ts * w1v.y + b1v.x;
        float t1 = ts * w1v.w + b1v.y;
        A2 = w1v.x*w1v.x + w1v.z*w1v.z;
        AC = w1v.x*t0    + w1v.z*t1;
        C2 = t0*t0       + t1*t1;
        #pragma unroll
        for (int m = 32; m >= 1; m >>= 1) {
            A2 += __shfl_xor(A2, m, 64);
            AC += __shfl_xor(AC, m, 64);
            C2 += __shfl_xor(C2, m, 64);
        }
    }

    if constexpr (!WS) {
        // fallback: stage W2 into LDS (bf16, 16B chunks XOR-swizzled by row&15)
        for (int idx = tid; idx < HID * 16; idx += BLK) {
            int row = idx >> 4, c = idx & 15;
            const float* src = W2 + row * HID + c * 8;
            float4 lo = *(const float4*)src;
            float4 hi = *(const float4*)(src + 4);
            uint4 pk;
            pk.x = (uint32_t)f2bf(lo.x) | ((uint32_t)f2bf(lo.y) << 16);
            pk.y = (uint32_t)f2bf(lo.z) | ((uint32_t)f2bf(lo.w) << 16);
            pk.z = (uint32_t)f2bf(hi.x) | ((uint32_t)f2bf(hi.y) << 16);
            pk.w = (uint32_t)f2bf(hi.z) | ((uint32_t)f2bf(hi.w) << 16);
            *((uint4*)&sm.w2l[row * 64 + 4 * (c ^ (row & 15))]) = pk;
        }
        __syncthreads();      // only barrier, fallback path only
    }

    if (lane == 0) sm.cnt[wid] = 0;   // same-wave DS program order covers later use

    const float px = pos[3*i], py = pos[3*i+1], pz = pos[3*i+2];
    const float4* p4 = (const float4*)pos;

    // ---- pass 1: per-lane sample min over its 64 j's ----
    float mind = FINF;
    for (int g = 0; g < 16; ++g) {
        float d[4];
        dist4(p4, g, lane, px, py, pz, i, d);
        mind = fminf(fminf(fminf(mind, d[0]), fminf(d[1], d[2])), d[3]);
    }
    const uint32_t m16 = __float_as_uint(mind) >> 16;

    // ---- s32 = 32nd smallest sample-min (16-bit radix search via ballot) ----
    // >=32 sample-mins at DISTINCT j (lanes own disjoint j sets, self excluded)
    // are <= s32  =>  the 32 smallest (d16,j) keys all have d16 <= s32.
    uint32_t v = 0;
    #pragma unroll
    for (int b = 15; b >= 0; --b) {
        uint32_t t = v | (1u << b);
        int nl = (int)__popcll(__ballot(m16 < t));
        if (nl < KK) v = t;
    }

    // ---- compaction: recompute distances; push keys with d16 <= s32 ----
    for (int g = 0; g < 16; ++g) {
        float d[4];
        dist4(p4, g, lane, px, py, pz, i, d);
        #pragma unroll
        for (int c = 0; c < 4; ++c) {
            uint32_t d16 = __float_as_uint(d[c]) >> 16;   // self=inf -> 0x7F80 > v
            if (d16 <= v) {
                int slot = atomicAdd(&sm.cnt[wid], 1);
                if (slot < CAP)
                    sm.cand[wid][slot] = (d16 << 16) | (unsigned)(g*256 + 4*lane + c);
            }
        }
    }
    const int cntv = sm.cnt[wid];   // wave-local; ordered by DS program order

    if (cntv <= CAP) {
        // ---- rank-select: lane ranks cand[lane] and cand[64+lane] ----
        #pragma unroll
        for (int h = 0; h < 2; ++h) {
            int idx = h*64 + lane;
            if (idx < cntv) {
                uint32_t km = sm.cand[wid][idx];
                int rank = 0;
                for (int q = 0; q < cntv; q += 4) {
                    uint4 u = *((const uint4*)&sm.cand[wid][q]);
                    rank += (q     < cntv && u.x < km) ? 1 : 0;
                    rank += (q + 1 < cntv && u.y < km) ? 1 : 0;
                    rank += (q + 2 < cntv && u.z < km) ? 1 : 0;
                    rank += (q + 3 < cntv && u.w < km) ? 1 : 0;
                }
                if (rank < KK) sm.recvs[wid][rank] = (int)(km & 0xFFFFu);
            }
        }
    } else {
        // ---- cold fallback (overflow; ~never): exact wave-local argmin x32,
        //      per-lane 64-bit exclusion mask for its own j's ----
        unsigned long long locmask = 0ull;
        for (int it = 0; it < KK; ++it) {
            unsigned long long best = ~0ull;
            for (int g = 0; g < 16; ++g) {
                float d[4];
                dist4(p4, g, lane, px, py, pz, i, d);
                #pragma unroll
                for (int c = 0; c < 4; ++c) {
                    bool dead = ((locmask >> (g*4 + c)) & 1ull) != 0ull;
                    unsigned long long key = dead ? ~0ull
                        : ((((unsigned long long)__float_as_uint(d[c])) << 12)
                           | (unsigned)(g*256 + 4*lane + c));
                    best = best < key ? best : key;
                }
            }
            #pragma unroll
            for (int m = 32; m >= 1; m >>= 1) {
                unsigned long long o = __shfl_xor(best, m, 64);
                best = best < o ? best : o;
            }
            int j = (int)(best & 0xfffull);
            if (lane == 0) sm.recvs[wid][it] = j;
            if (((j >> 2) & 63) == lane)
                locmask |= 1ull << ((j >> 8) * 4 + (j & 3));
        }
    }

    // ---- edge gather: lane e < 32 holds neighbor e's geometry ----
    float cdx = 0.f, cdy = 0.f, cdz = 0.f;
    if (lane < KK) {
        int r = sm.recvs[wid][lane];
        cdx = px - pos[3*r];
        cdy = py - pos[3*r+1];
        cdz = pz - pos[3*r+2];
        float rad = __fadd_rn(__fadd_rn(__fmul_rn(cdx,cdx), __fmul_rn(cdy,cdy)),
                              __fmul_rn(cdz,cdz));
        sm.rads[wid][lane] = rad;
    }

    // ---- layer 1: all 32 edges of this node; lane = ch*4 + epr ----
    {
        const int ch = lane >> 2, epr = lane & 3;
        float4 wA = ((const float4*)W1)[ch*4    ];
        float4 wB = ((const float4*)W1)[ch*4 + 1];
        float4 wC = ((const float4*)W1)[ch*4 + 2];
        float4 wD = ((const float4*)W1)[ch*4 + 3];
        float4 bA = ((const float4*)b1)[ch*2], bB = ((const float4*)b1)[ch*2 + 1];
        float4 gA = ((const float4*)g1)[ch*2], gB = ((const float4*)g1)[ch*2 + 1];
        float av[8] = {wA.x, wA.z, wB.x, wB.z, wC.x, wC.z, wD.x, wD.z};
        float cv[8] = {ts*wA.y + bA.x, ts*wA.w + bA.y, ts*wB.y + bA.z, ts*wB.w + bA.w,
                       ts*wC.y + bB.x, ts*wC.w + bB.y, ts*wD.y + bB.z, ts*wD.w + bB.w};
        float gv[8] = {gA.x, gA.y, gA.z, gA.w, gB.x, gB.y, gB.z, gB.w};
        uint4* h1q = (uint4*)&sm.h1[wid][0];
        #pragma unroll
        for (int g = 0; g < 8; ++g) {
            int E = 4*g + epr;                    // 0..31
            float rad = sm.rads[wid][E];
            float sqv = rad*rad*A2 + 2.0f*rad*AC + C2;
            float rn  = rsqrtf(sqv * (1.0f/HID) + 1e-5f);
            uint32_t pk[4];
            #pragma unroll
            for (int p = 0; p < 4; ++p) {
                float va = siluf((rad*av[2*p]   + cv[2*p])   * rn * gv[2*p]);
                float vb = siluf((rad*av[2*p+1] + cv[2*p+1]) * rn * gv[2*p+1]);
                pk[p] = (__float_as_uint(va) >> 16) | (__float_as_uint(vb) & 0xffff0000u);
            }
            h1q[E*16 + (ch ^ (E & 15))] = uint4{pk[0], pk[1], pk[2], pk[3]};
        }
    }
    // no barrier: h1[wid] written and read only by this wave (DS program order)

    // ---- epilogue constants: n = nt*16 + l15 (shared by both m-tile passes) ----
    float g2v[8], w3v[8], b2v[8];
    #pragma unroll
    for (int nt = 0; nt < 8; ++nt) {
        int n = nt*16 + l15;
        g2v[nt] = g2[n]; w3v[nt] = W3[n]; b2v[nt] = b2[n];
    }

    // ---- layer 2 + epilogue: two m-tile passes (16 edges each), all 8 n-tiles ----
    const bf16x8* h1v = (const bf16x8*)&sm.h1[wid][0];
    #pragma unroll
    for (int mt = 0; mt < 2; ++mt) {
        f32x4 acc[8];
        #pragma unroll
        for (int nt = 0; nt < 8; ++nt) acc[nt] = f32x4{0.f, 0.f, 0.f, 0.f};
        const int m = mt*16 + l15;
        if constexpr (WS) {
            const bf16x8* bv = (const bf16x8*)w2b;
            #pragma unroll
            for (int kk = 0; kk < 4; ++kk) {
                bf16x8 af = h1v[m*16 + ((kk*4 + lq) ^ l15)];
                #pragma unroll
                for (int nt = 0; nt < 8; ++nt)
                    acc[nt] = __builtin_amdgcn_mfma_f32_16x16x32_bf16(
                                  af, bv[(nt*4 + kk)*64 + lane], acc[nt], 0, 0, 0);
            }
        } else {
            const bf16x8* w2v = (const bf16x8*)sm.w2l;    // [128][16 chunks]
            #pragma unroll
            for (int kk = 0; kk < 4; ++kk) {
                const int q = (kk*4 + lq) ^ l15;
                bf16x8 af = h1v[m*16 + q];
                #pragma unroll
                for (int nt = 0; nt < 8; ++nt)
                    acc[nt] = __builtin_amdgcn_mfma_f32_16x16x32_bf16(
                                  af, w2v[(nt*16 + l15)*16 + q], acc[nt], 0, 0, 0);
            }
        }

        // RMS over all 128 neurons: in-lane sum over 8 nt + shfl over l15 bits
        float ss[4];
        #pragma unroll
        for (int r = 0; r < 4; ++r) {
            float t = 0.f;
            #pragma unroll
            for (int nt = 0; nt < 8; ++nt) {
                float zz = acc[nt][r] + b2v[nt];
                acc[nt][r] = zz;
                t += zz*zz;
            }
            ss[r] = t;
        }
        #pragma unroll
        for (int m2 = 1; m2 <= 8; m2 <<= 1) {
            #pragma unroll
            for (int r = 0; r < 4; ++r) ss[r] += __shfl_xor(ss[r], m2, 64);
        }
        float sp[4];
        #pragma unroll
        for (int r = 0; r < 4; ++r) {
            float rn = rsqrtf(ss[r] * (1.0f/HID) + 1e-5f);
            float t = 0.f;
            #pragma unroll
            for (int nt = 0; nt < 8; ++nt)
                t += siluf(acc[nt][r] * rn * g2v[nt]) * w3v[nt];
            sp[r] = t;
        }
        #pragma unroll
        for (int m2 = 1; m2 <= 8; m2 <<= 1) {
            #pragma unroll
            for (int r = 0; r < 4; ++r) sp[r] += __shfl_xor(sp[r], m2, 64);
        }
        if (l15 == 0) {
            #pragma unroll
            for (int r = 0; r < 4; ++r)
                sm.sedge[wid][mt*16 + lq*4 + r] = sp[r] + b3s;
        }
    }

    // ---- final: sum 32 edge messages (lane e holds cd of edge e) ----
    float mx = 0.f, my = 0.f, mz = 0.f;
    if (lane < KK) {
        float s = sm.sedge[wid][lane];
        mx = cdx * s; my = cdy * s; mz = cdz * s;
    }
    #pragma unroll
    for (int m = 32; m >= 1; m >>= 1) {
        mx += __shfl_xor(mx, m, 64);
        my += __shfl_xor(my, m, 64);
        mz += __shfl_xor(mz, m, 64);
    }
    if (lane == 0) {
        out[3*i    ] = px + mx * (1.0f/KK);
        out[3*i + 1] = py + my * (1.0f/KK);
        out[3*i + 2] = pz + mz * (1.0f/KK);
    }
}

extern "C" void kernel_launch(void* const* d_in, const int* in_sizes, int n_in,
                              void* d_out, int out_size, void* d_ws, size_t ws_size,
                              hipStream_t stream) {
    (void)in_sizes; (void)n_in; (void)out_size;
    const float* pos = (const float*)d_in[0];
    const float* t   = (const float*)d_in[1];
    const float* W1  = (const float*)d_in[2];
    const float* b1  = (const float*)d_in[3];
    const float* g1  = (const float*)d_in[4];
    const float* W2  = (const float*)d_in[5];
    const float* b2  = (const float*)d_in[6];
    const float* g2  = (const float*)d_in[7];
    const float* W3  = (const float*)d_in[8];
    const float* b3  = (const float*)d_in[9];
    float* out = (float*)d_out;

    if (d_ws != nullptr && ws_size >= 32768) {
        prepack_w2<<<8, 256, 0, stream>>>(W2, (uint4*)d_ws);
        egnn_main<true><<<GRID, BLK, 0, stream>>>(
            pos, t, W1, b1, g1, W2, b2, g2, W3, b3, (const uint4*)d_ws, out);
    } else {
        egnn_main<false><<<GRID, BLK, 0, stream>>>(
            pos, t, W1, b1, g1, W2, b2, g2, W3, b3, nullptr, out);
    }
}

// Round 18
// 114.548 us; speedup vs baseline: 1.1775x; 1.0552x over previous
//
#include <hip/hip_runtime.h>
#include <stdint.h>

#define NN   4096
#define KK   32
#define HID  128
#define BLK  256
#define WPB  4                 // waves per block = nodes per block
#define GRID (NN / WPB)
#define CAP  128

typedef unsigned short bf16_t;
typedef __attribute__((ext_vector_type(8))) short bf16x8;
typedef __attribute__((ext_vector_type(4))) float f32x4;

#define FINF __uint_as_float(0x7f800000u)

__device__ __forceinline__ bf16_t f2bf(float f) {
    uint32_t u = __float_as_uint(f);
    u = u + 0x7fffu + ((u >> 16) & 1u);   // round-to-nearest-even
    return (bf16_t)(u >> 16);
}
__device__ __forceinline__ float siluf(float x) {
    return x / (1.0f + __expf(-x));
}

// 4 distances for j = g*256 + 4*lane + c (exact fp32 chain; self -> inf)
__device__ __forceinline__ void dist4(const float4* __restrict__ p4, int g, int lane,
                                      float px, float py, float pz, int iself,
                                      float d[4]) {
    float4 f0 = p4[g*192 + 3*lane];
    float4 f1 = p4[g*192 + 3*lane + 1];
    float4 f2 = p4[g*192 + 3*lane + 2];
    float jx[4] = {f0.x, f0.w, f1.z, f2.y};
    float jy[4] = {f0.y, f1.x, f1.w, f2.z};
    float jz[4] = {f0.z, f1.y, f2.x, f2.w};
    #pragma unroll
    for (int c = 0; c < 4; ++c) {
        int j = g*256 + 4*lane + c;
        float dx = px - jx[c], dy = py - jy[c], dz = pz - jz[c];
        float dd = __fadd_rn(__fadd_rn(__fmul_rn(dx,dx), __fmul_rn(dy,dy)),
                             __fmul_rn(dz,dz));
        d[c] = (j == iself) ? FINF : dd;
    }
}

// ---- prepack: W2 fp32 -> bf16 in MFMA B-fragment order (frag f = NT*4+kk) ----
__global__ __launch_bounds__(256) void prepack_w2(
    const float* __restrict__ W2, uint4* __restrict__ w2b)
{
    int c  = blockIdx.x * 256 + threadIdx.x;
    int f  = c >> 6, ln = c & 63;
    int NT = f >> 2, kk = f & 3;
    int row = NT*16 + (ln & 15);
    int k0  = kk*32 + (ln >> 4) * 8;
    const float* s = W2 + row * HID + k0;
    float4 lo = *(const float4*)s;
    float4 hi = *(const float4*)(s + 4);
    uint4 pk;
    pk.x = (uint32_t)f2bf(lo.x) | ((uint32_t)f2bf(lo.y) << 16);
    pk.y = (uint32_t)f2bf(lo.z) | ((uint32_t)f2bf(lo.w) << 16);
    pk.z = (uint32_t)f2bf(hi.x) | ((uint32_t)f2bf(hi.y) << 16);
    pk.w = (uint32_t)f2bf(hi.z) | ((uint32_t)f2bf(hi.w) << 16);
    w2b[c] = pk;
}

template<bool WS>
struct __align__(16) Sm {
    // per-wave 8 KB region: dbf (selection phase) then h1 (MLP phase) — same-wave
    // program order makes the union safe with no barrier.
    union __align__(16) U {
        ushort dbf[NN];                 // top-16 distance bits per j
        ushort h1[KK * HID];            // MLP A-operand (32 edges x 128, swizzled)
    } uw[WPB];                          // 32 KB total
    uint32_t cand[WPB][CAP];            // 2 KB : per-wave (d16<<16)|j keys
    float    rads[WPB][KK];             // per-wave edge radial
    float    sedge[WPB][KK];            // per-wave edge scalar
    int      recvs[WPB][KK];            // per-wave neighbor ids
    uint32_t w2l[WS ? 4 : HID * 64];    // W2 LDS staging only in no-workspace path
};

template<bool WS>
__global__ __launch_bounds__(BLK) void egnn_main(
    const float* __restrict__ pos, const float* __restrict__ tptr,
    const float* __restrict__ W1,  const float* __restrict__ b1,
    const float* __restrict__ g1,  const float* __restrict__ W2,
    const float* __restrict__ b2,  const float* __restrict__ g2,
    const float* __restrict__ W3,  const float* __restrict__ b3,
    const uint4* __restrict__ w2b, float* __restrict__ out)
{
    __shared__ Sm<WS> sm;
    const int tid  = threadIdx.x;
    const int lane = tid & 63;
    const int wid  = tid >> 6;                  // 0..3: this wave / its node
    const int i    = blockIdx.x * WPB + wid;    // node handled by this wave
    const int l15  = lane & 15, lq = lane >> 4;

    const float ts  = tptr[0];
    const float b3s = b3[0];

    // closed-form RMS coefficients (wave-reduced -> lane-uniform):
    // sum_n (rad*a_n + c_n)^2 = rad^2*A2 + 2*rad*AC + C2
    float A2, AC, C2;
    {
        const float4 w1v = ((const float4*)W1)[lane];     // rows 2l,2l+1
        const float2 b1v = ((const float2*)b1)[lane];
        float t0 = ts * w1v.y + b1v.x;
        float t1 = ts * w1v.w + b1v.y;
        A2 = w1v.x*w1v.x + w1v.z*w1v.z;
        AC = w1v.x*t0    + w1v.z*t1;
        C2 = t0*t0       + t1*t1;
        #pragma unroll
        for (int m = 32; m >= 1; m >>= 1) {
            A2 += __shfl_xor(A2, m, 64);
            AC += __shfl_xor(AC, m, 64);
            C2 += __shfl_xor(C2, m, 64);
        }
    }

    if constexpr (!WS) {
        // fallback: stage W2 into LDS (bf16, 16B chunks XOR-swizzled by row&15)
        for (int idx = tid; idx < HID * 16; idx += BLK) {
            int row = idx >> 4, c = idx & 15;
            const float* src = W2 + row * HID + c * 8;
            float4 lo = *(const float4*)src;
            float4 hi = *(const float4*)(src + 4);
            uint4 pk;
            pk.x = (uint32_t)f2bf(lo.x) | ((uint32_t)f2bf(lo.y) << 16);
            pk.y = (uint32_t)f2bf(lo.z) | ((uint32_t)f2bf(lo.w) << 16);
            pk.z = (uint32_t)f2bf(hi.x) | ((uint32_t)f2bf(hi.y) << 16);
            pk.w = (uint32_t)f2bf(hi.z) | ((uint32_t)f2bf(hi.w) << 16);
            *((uint4*)&sm.w2l[row * 64 + 4 * (c ^ (row & 15))]) = pk;
        }
        __syncthreads();      // only barrier, fallback path only
    }

    const float px = pos[3*i], py = pos[3*i+1], pz = pos[3*i+2];
    const float4* p4 = (const float4*)pos;

    // ---- pass 1: distances ONCE; d16 to per-wave LDS; per-lane sample min ----
    float mind = FINF;
    {
        ushort* dbf = sm.uw[wid].dbf;
        #pragma unroll 4
        for (int g = 0; g < 16; ++g) {
            float d[4];
            dist4(p4, g, lane, px, py, pz, i, d);
            uint32_t lo = (__float_as_uint(d[0]) >> 16) | (__float_as_uint(d[1]) & 0xffff0000u);
            uint32_t hi = (__float_as_uint(d[2]) >> 16) | (__float_as_uint(d[3]) & 0xffff0000u);
            *((uint2*)&dbf[g*256 + 4*lane]) = make_uint2(lo, hi);
            mind = fminf(fminf(fminf(mind, d[0]), fminf(d[1], d[2])), d[3]);
        }
    }
    const uint32_t m16 = __float_as_uint(mind) >> 16;

    // ---- v = 32nd smallest sample-min (16-bit radix search via ballot) ----
    // >=32 sample-mins at DISTINCT j (lanes own disjoint j sets, self excluded)
    // are <= v  =>  the 32 smallest (d16,j) keys all have d16 <= v.
    uint32_t v = 0;
    #pragma unroll
    for (int b = 15; b >= 0; --b) {
        uint32_t t = v | (1u << b);
        int nl = (int)__popcll(__ballot(m16 < t));
        if (nl < KK) v = t;
    }

    // ---- compaction from LDS d16, ballot+prefix (no atomics, no recompute) ----
    uint32_t cnt = 0;
    {
        const ushort* dbf = sm.uw[wid].dbf;
        const unsigned long long below = (1ull << lane) - 1ull;
        for (int g = 0; g < 16; ++g) {
            uint2 w = *((const uint2*)&dbf[g*256 + 4*lane]);
            uint32_t d16v[4] = {w.x & 0xffffu, w.x >> 16, w.y & 0xffffu, w.y >> 16};
            #pragma unroll
            for (int c = 0; c < 4; ++c) {
                bool pred = d16v[c] <= v;       // self=inf -> 0x7F80 > v
                unsigned long long mb = __ballot(pred);
                if (pred) {
                    int slot = (int)cnt + (int)__popcll(mb & below);
                    if (slot < CAP)
                        sm.cand[wid][slot] = (d16v[c] << 16)
                                           | (unsigned)(g*256 + 4*lane + c);
                }
                cnt += (uint32_t)__popcll(mb);  // wave-uniform
            }
        }
    }
    const int cntv = (int)cnt;

    if (cntv <= CAP) {
        // ---- rank-select: lane ranks cand[lane] and cand[64+lane] ----
        #pragma unroll
        for (int h = 0; h < 2; ++h) {
            int idx = h*64 + lane;
            if (idx < cntv) {
                uint32_t km = sm.cand[wid][idx];
                int rank = 0;
                for (int q = 0; q < cntv; q += 4) {
                    uint4 u = *((const uint4*)&sm.cand[wid][q]);
                    rank += (q     < cntv && u.x < km) ? 1 : 0;
                    rank += (q + 1 < cntv && u.y < km) ? 1 : 0;
                    rank += (q + 2 < cntv && u.z < km) ? 1 : 0;
                    rank += (q + 3 < cntv && u.w < km) ? 1 : 0;
                }
                if (rank < KK) sm.recvs[wid][rank] = (int)(km & 0xFFFFu);
            }
        }
    } else {
        // ---- cold fallback (overflow; ~never): exact wave-local argmin x32,
        //      per-lane 64-bit exclusion mask for its own j's (recompute) ----
        unsigned long long locmask = 0ull;
        for (int it = 0; it < KK; ++it) {
            unsigned long long best = ~0ull;
            for (int g = 0; g < 16; ++g) {
                float d[4];
                dist4(p4, g, lane, px, py, pz, i, d);
                #pragma unroll
                for (int c = 0; c < 4; ++c) {
                    bool dead = ((locmask >> (g*4 + c)) & 1ull) != 0ull;
                    unsigned long long key = dead ? ~0ull
                        : ((((unsigned long long)__float_as_uint(d[c])) << 12)
                           | (unsigned)(g*256 + 4*lane + c));
                    best = best < key ? best : key;
                }
            }
            #pragma unroll
            for (int m = 32; m >= 1; m >>= 1) {
                unsigned long long o = __shfl_xor(best, m, 64);
                best = best < o ? best : o;
            }
            int j = (int)(best & 0xfffull);
            if (lane == 0) sm.recvs[wid][it] = j;
            if (((j >> 2) & 63) == lane)
                locmask |= 1ull << ((j >> 8) * 4 + (j & 3));
        }
    }

    // ---- edge gather: lane e < 32 holds neighbor e's geometry ----
    float cdx = 0.f, cdy = 0.f, cdz = 0.f;
    if (lane < KK) {
        int r = sm.recvs[wid][lane];
        cdx = px - pos[3*r];
        cdy = py - pos[3*r+1];
        cdz = pz - pos[3*r+2];
        float rad = __fadd_rn(__fadd_rn(__fmul_rn(cdx,cdx), __fmul_rn(cdy,cdy)),
                              __fmul_rn(cdz,cdz));
        sm.rads[wid][lane] = rad;
    }

    // ---- layer 1: all 32 edges of this node; lane = ch*4 + epr ----
    // h1 overwrites dbf (same union region) — all dbf reads completed above in
    // this wave's program order.
    {
        const int ch = lane >> 2, epr = lane & 3;
        float4 wA = ((const float4*)W1)[ch*4    ];
        float4 wB = ((const float4*)W1)[ch*4 + 1];
        float4 wC = ((const float4*)W1)[ch*4 + 2];
        float4 wD = ((const float4*)W1)[ch*4 + 3];
        float4 bA = ((const float4*)b1)[ch*2], bB = ((const float4*)b1)[ch*2 + 1];
        float4 gA = ((const float4*)g1)[ch*2], gB = ((const float4*)g1)[ch*2 + 1];
        float av[8] = {wA.x, wA.z, wB.x, wB.z, wC.x, wC.z, wD.x, wD.z};
        float cv[8] = {ts*wA.y + bA.x, ts*wA.w + bA.y, ts*wB.y + bA.z, ts*wB.w + bA.w,
                       ts*wC.y + bB.x, ts*wC.w + bB.y, ts*wD.y + bB.z, ts*wD.w + bB.w};
        float gv[8] = {gA.x, gA.y, gA.z, gA.w, gB.x, gB.y, gB.z, gB.w};
        uint4* h1q = (uint4*)&sm.uw[wid].h1[0];
        #pragma unroll
        for (int g = 0; g < 8; ++g) {
            int E = 4*g + epr;                    // 0..31
            float rad = sm.rads[wid][E];
            float sqv = rad*rad*A2 + 2.0f*rad*AC + C2;
            float rn  = rsqrtf(sqv * (1.0f/HID) + 1e-5f);
            uint32_t pk[4];
            #pragma unroll
            for (int p = 0; p < 4; ++p) {
                float va = siluf((rad*av[2*p]   + cv[2*p])   * rn * gv[2*p]);
                float vb = siluf((rad*av[2*p+1] + cv[2*p+1]) * rn * gv[2*p+1]);
                pk[p] = (__float_as_uint(va) >> 16) | (__float_as_uint(vb) & 0xffff0000u);
            }
            h1q[E*16 + (ch ^ (E & 15))] = uint4{pk[0], pk[1], pk[2], pk[3]};
        }
    }
    // no barrier: h1[wid] written and read only by this wave (DS program order)

    // ---- epilogue constants: n = nt*16 + l15 (shared by both m-tile passes) ----
    float g2v[8], w3v[8], b2v[8];
    #pragma unroll
    for (int nt = 0; nt < 8; ++nt) {
        int n = nt*16 + l15;
        g2v[nt] = g2[n]; w3v[nt] = W3[n]; b2v[nt] = b2[n];
    }

    // ---- layer 2 + epilogue: two m-tile passes (16 edges each), all 8 n-tiles ----
    const bf16x8* h1v = (const bf16x8*)&sm.uw[wid].h1[0];
    #pragma unroll
    for (int mt = 0; mt < 2; ++mt) {
        f32x4 acc[8];
        #pragma unroll
        for (int nt = 0; nt < 8; ++nt) acc[nt] = f32x4{0.f, 0.f, 0.f, 0.f};
        const int m = mt*16 + l15;
        if constexpr (WS) {
            const bf16x8* bv = (const bf16x8*)w2b;
            #pragma unroll
            for (int kk = 0; kk < 4; ++kk) {
                bf16x8 af = h1v[m*16 + ((kk*4 + lq) ^ l15)];
                #pragma unroll
                for (int nt = 0; nt < 8; ++nt)
                    acc[nt] = __builtin_amdgcn_mfma_f32_16x16x32_bf16(
                                  af, bv[(nt*4 + kk)*64 + lane], acc[nt], 0, 0, 0);
            }
        } else {
            const bf16x8* w2v = (const bf16x8*)sm.w2l;    // [128][16 chunks]
            #pragma unroll
            for (int kk = 0; kk < 4; ++kk) {
                const int q = (kk*4 + lq) ^ l15;
                bf16x8 af = h1v[m*16 + q];
                #pragma unroll
                for (int nt = 0; nt < 8; ++nt)
                    acc[nt] = __builtin_amdgcn_mfma_f32_16x16x32_bf16(
                                  af, w2v[(nt*16 + l15)*16 + q], acc[nt], 0, 0, 0);
            }
        }

        // RMS over all 128 neurons: in-lane sum over 8 nt + shfl over l15 bits
        float ss[4];
        #pragma unroll
        for (int r = 0; r < 4; ++r) {
            float t = 0.f;
            #pragma unroll
            for (int nt = 0; nt < 8; ++nt) {
                float zz = acc[nt][r] + b2v[nt];
                acc[nt][r] = zz;
                t += zz*zz;
            }
            ss[r] = t;
        }
        #pragma unroll
        for (int m2 = 1; m2 <= 8; m2 <<= 1) {
            #pragma unroll
            for (int r = 0; r < 4; ++r) ss[r] += __shfl_xor(ss[r], m2, 64);
        }
        float sp[4];
        #pragma unroll
        for (int r = 0; r < 4; ++r) {
            float rn = rsqrtf(ss[r] * (1.0f/HID) + 1e-5f);
            float t = 0.f;
            #pragma unroll
            for (int nt = 0; nt < 8; ++nt)
                t += siluf(acc[nt][r] * rn * g2v[nt]) * w3v[nt];
            sp[r] = t;
        }
        #pragma unroll
        for (int m2 = 1; m2 <= 8; m2 <<= 1) {
            #pragma unroll
            for (int r = 0; r < 4; ++r) sp[r] += __shfl_xor(sp[r], m2, 64);
        }
        if (l15 == 0) {
            #pragma unroll
            for (int r = 0; r < 4; ++r)
                sm.sedge[wid][mt*16 + lq*4 + r] = sp[r] + b3s;
        }
    }

    // ---- final: sum 32 edge messages (lane e holds cd of edge e) ----
    float mx = 0.f, my = 0.f, mz = 0.f;
    if (lane < KK) {
        float s = sm.sedge[wid][lane];
        mx = cdx * s; my = cdy * s; mz = cdz * s;
    }
    #pragma unroll
    for (int m = 32; m >= 1; m >>= 1) {
        mx += __shfl_xor(mx, m, 64);
        my += __shfl_xor(my, m, 64);
        mz += __shfl_xor(mz, m, 64);
    }
    if (lane == 0) {
        out[3*i    ] = px + mx * (1.0f/KK);
        out[3*i + 1] = py + my * (1.0f/KK);
        out[3*i + 2] = pz + mz * (1.0f/KK);
    }
}

extern "C" void kernel_launch(void* const* d_in, const int* in_sizes, int n_in,
                              void* d_out, int out_size, void* d_ws, size_t ws_size,
                              hipStream_t stream) {
    (void)in_sizes; (void)n_in; (void)out_size;
    const float* pos = (const float*)d_in[0];
    const float* t   = (const float*)d_in[1];
    const float* W1  = (const float*)d_in[2];
    const float* b1  = (const float*)d_in[3];
    const float* g1  = (const float*)d_in[4];
    const float* W2  = (const float*)d_in[5];
    const float* b2  = (const float*)d_in[6];
    const float* g2  = (const float*)d_in[7];
    const float* W3  = (const float*)d_in[8];
    const float* b3  = (const float*)d_in[9];
    float* out = (float*)d_out;

    if (d_ws != nullptr && ws_size >= 32768) {
        prepack_w2<<<8, 256, 0, stream>>>(W2, (uint4*)d_ws);
        egnn_main<true><<<GRID, BLK, 0, stream>>>(
            pos, t, W1, b1, g1, W2, b2, g2, W3, b3, (const uint4*)d_ws, out);
    } else {
        egnn_main<false><<<GRID, BLK, 0, stream>>>(
            pos, t, W1, b1, g1, W2, b2, g2, W3, b3, nullptr, out);
    }
}